// Round 1
// baseline (165.915 us; speedup 1.0000x reference)
//
#include <hip/hip_runtime.h>

#define PI_F      3.14159265358979f
#define TWO_PI_F  6.28318530717959f
#define ALPHA_F   0.3f
#define NT        256

// sin/cos of 2*pi*u using the hardware trig units (input in revolutions).
__device__ __forceinline__ void sincos2pi(float u, float& s, float& c) {
    float uf = u - floorf(u);   // range-reduce to [0,1) revolutions
    asm("v_sin_f32 %0, %1" : "=v"(s) : "v"(uf));
    asm("v_cos_f32 %0, %1" : "=v"(c) : "v"(uf));
}

// ---------------- box inverse + volume ----------------
__global__ void k_box(const float* __restrict__ box, float* __restrict__ head) {
    if (threadIdx.x != 0 || blockIdx.x != 0) return;
    float b00=box[0], b01=box[1], b02=box[2];
    float b10=box[3], b11=box[4], b12=box[5];
    float b20=box[6], b21=box[7], b22=box[8];
    float c00 = b11*b22 - b12*b21;
    float c01 = b02*b21 - b01*b22;
    float c02 = b01*b12 - b02*b11;
    float c10 = b12*b20 - b10*b22;
    float c11 = b00*b22 - b02*b20;
    float c12 = b02*b10 - b00*b12;
    float c20 = b10*b21 - b11*b20;
    float c21 = b01*b20 - b00*b21;
    float c22 = b00*b11 - b01*b10;
    float det = b00*c00 + b01*c10 + b02*c20;
    float id = 1.0f/det;
    head[0]=c00*id; head[1]=c01*id; head[2]=c02*id;
    head[3]=c10*id; head[4]=c11*id; head[5]=c12*id;
    head[6]=c20*id; head[7]=c21*id; head[8]=c22*id;
    head[9]=det;  // V
}

// ---------------- k-vector prep: pk1[k][16] = {ax,ay,az,axx,ayy,azz,axy,axz,ayz,g,...}
//                  pk2[k][8]  = {ax,ay,az, (SrG,SiG filled later), ...}
__global__ void k_kvec(const float* __restrict__ kvecs, const float* __restrict__ head,
                       float* __restrict__ pk1, float* __restrict__ pk2, int K) {
    int k = blockIdx.x*NT + threadIdx.x;
    if (k >= K) return;
    float b0=head[0],b1=head[1],b2=head[2],b3=head[3],b4=head[4],
          b5=head[5],b6=head[6],b7=head[7],b8=head[8];
    float kx=kvecs[3*k], ky=kvecs[3*k+1], kz=kvecs[3*k+2];
    float ax = kx*b0 + ky*b3 + kz*b6;
    float ay = kx*b1 + ky*b4 + kz*b7;
    float az = kx*b2 + ky*b5 + kz*b8;
    float ksq = ax*ax + ay*ay + az*az;
    float g = expf(-PI_F*PI_F*ksq/(ALPHA_F*ALPHA_F)) / ksq;
    float* o = pk1 + 16*(size_t)k;
    o[0]=ax; o[1]=ay; o[2]=az;
    o[3]=ax*ax; o[4]=ay*ay; o[5]=az*az;
    o[6]=ax*ay; o[7]=ax*az; o[8]=ay*az;
    o[9]=g; o[10]=0.f; o[11]=0.f; o[12]=0.f; o[13]=0.f; o[14]=0.f; o[15]=0.f;
    float* o2 = pk2 + 8*(size_t)k;
    o2[0]=ax; o2[1]=ay; o2[2]=az; o2[5]=0.f; o2[6]=0.f; o2[7]=0.f;
}

// ---------------- atom prep: atom16[n][16] = {rx,ry,rz,q, 2pi*p(3), scaled sym t(6), pad}
__global__ void k_atoms(const float* __restrict__ coords, const float* __restrict__ q,
                        const float* __restrict__ p, const float* __restrict__ t,
                        float* __restrict__ atom16, int N) {
    int n = blockIdx.x*NT + threadIdx.x;
    if (n >= N) return;
    const float c1 = TWO_PI_F*TWO_PI_F/3.0f;
    const float* tn = t + 9*(size_t)n;
    float* o = atom16 + 16*(size_t)n;
    o[0]=coords[3*n]; o[1]=coords[3*n+1]; o[2]=coords[3*n+2];
    o[3]=q[n];
    o[4]=TWO_PI_F*p[3*n]; o[5]=TWO_PI_F*p[3*n+1]; o[6]=TWO_PI_F*p[3*n+2];
    o[7]=c1*tn[0]; o[8]=c1*tn[4]; o[9]=c1*tn[8];
    o[10]=c1*(tn[1]+tn[3]); o[11]=c1*(tn[2]+tn[6]); o[12]=c1*(tn[5]+tn[7]);
    o[13]=0.f; o[14]=0.f; o[15]=0.f;
}

// ---------------- self-energy sums: selfs = {sum q^2, sum |p|^2, sum t^2}
__global__ void k_self(const float* __restrict__ q, const float* __restrict__ p,
                       const float* __restrict__ t, float* __restrict__ selfs, int N) {
    float sq=0.f, sp=0.f, st=0.f;
    for (int n = threadIdx.x; n < N; n += NT) {
        float qq=q[n]; sq = fmaf(qq,qq,sq);
        float p0=p[3*n],p1=p[3*n+1],p2=p[3*n+2];
        sp += p0*p0 + p1*p1 + p2*p2;
        const float* tn = t + 9*(size_t)n;
        #pragma unroll
        for (int j=0;j<9;++j) st = fmaf(tn[j],tn[j],st);
    }
    __shared__ float lds[3][4];
    int lane = threadIdx.x & 63, w = threadIdx.x >> 6;
    for (int o=32;o;o>>=1) {
        sq += __shfl_down(sq,o,64); sp += __shfl_down(sp,o,64); st += __shfl_down(st,o,64);
    }
    if (lane==0){ lds[0][w]=sq; lds[1][w]=sp; lds[2][w]=st; }
    __syncthreads();
    if (threadIdx.x==0){
        selfs[0]=lds[0][0]+lds[0][1]+lds[0][2]+lds[0][3];
        selfs[1]=lds[1][0]+lds[1][1]+lds[1][2]+lds[1][3];
        selfs[2]=lds[2][0]+lds[2][1]+lds[2][2]+lds[2][3];
    }
}

// ---------------- pass 1: lane = k, loop atoms (uniform scalar loads). partials over atom-splits.
__global__ __launch_bounds__(NT) void k_pass1(const float* __restrict__ pk1,
        const float* __restrict__ atom16, float* __restrict__ psr, float* __restrict__ psi,
        int N, int K) {
    int k = blockIdx.x*NT + threadIdx.x;
    int s = blockIdx.y;
    int nsplit = gridDim.y;
    int AC = (N + nsplit - 1)/nsplit;
    int n0 = s*AC, n1 = min(N, n0+AC);
    float ax=0,ay=0,az=0,axx=0,ayy=0,azz=0,axy=0,axz=0,ayz=0;
    if (k < K) {
        const float* o = pk1 + 16*(size_t)k;
        ax=o[0]; ay=o[1]; az=o[2]; axx=o[3]; ayy=o[4]; azz=o[5];
        axy=o[6]; axz=o[7]; ayz=o[8];
    }
    float sr=0.f, si=0.f;
    #pragma unroll 2
    for (int n = n0; n < n1; ++n) {
        const float* an = atom16 + 16*(size_t)n;   // uniform address -> s_load
        float rx=an[0], ry=an[1], rz=an[2], qn=an[3];
        float px=an[4], py=an[5], pz=an[6];
        float sxx=an[7], syy=an[8], szz=an[9], sxy=an[10], sxz=an[11], syz=an[12];
        float u = ax*rx + ay*ry + az*rz;
        float ss, cc; sincos2pi(u, ss, cc);
        float quad = axx*sxx + ayy*syy + azz*szz + axy*sxy + axz*sxz + ayz*syz;
        float Lr = qn - quad;
        float Li = ax*px + ay*py + az*pz;
        sr += cc*Lr - ss*Li;
        si += cc*Li + ss*Lr;
    }
    if (k < K) { psr[(size_t)s*K + k] = sr; psi[(size_t)s*K + k] = si; }
}

// ---------------- reduce pass-1 partials -> SrG/SiG in pk2, per-block energy partials
__global__ void k_reduce1(const float* __restrict__ pk1, const float* __restrict__ psr,
                          const float* __restrict__ psi, float* __restrict__ pk2,
                          float* __restrict__ eblk, int K, int nsplit) {
    int k = blockIdx.x*NT + threadIdx.x;
    float ek = 0.f;
    if (k < K) {
        float sr=0.f, si=0.f;
        for (int s=0;s<nsplit;++s){ sr += psr[(size_t)s*K+k]; si += psi[(size_t)s*K+k]; }
        float g = pk1[16*(size_t)k + 9];
        float srg = g*sr, sig = g*si;
        pk2[8*(size_t)k+3] = srg;
        pk2[8*(size_t)k+4] = sig;
        ek = srg*sr + sig*si;
    }
    __shared__ float lds[4];
    int lane = threadIdx.x & 63, w = threadIdx.x >> 6;
    for (int o=32;o;o>>=1) ek += __shfl_down(ek,o,64);
    if (lane==0) lds[w]=ek;
    __syncthreads();
    if (threadIdx.x==0) eblk[blockIdx.x] = lds[0]+lds[1]+lds[2]+lds[3];
}

// ---------------- energy final
__global__ void k_energy(const float* __restrict__ eblk, int nblk,
                         const float* __restrict__ selfs, const float* __restrict__ head,
                         float* __restrict__ out) {
    float e=0.f;
    for (int i=threadIdx.x;i<nblk;i+=64) e += eblk[i];
    for (int o=32;o;o>>=1) e += __shfl_down(e,o,64);
    if (threadIdx.x==0) {
        float V = head[9];
        float arpi = ALPHA_F/sqrtf(PI_F);
        float a2 = ALPHA_F*ALPHA_F;
        float energy = e/(PI_F*V)
                     - arpi*selfs[0]
                     - arpi*(2.0f*a2/3.0f)*selfs[1]
                     - arpi*(8.0f*a2*a2/45.0f)*selfs[2];
        out[0] = energy;
    }
}

// ---------------- pass 2: lane = atom, loop k (uniform scalar loads). partials over k-splits.
__global__ __launch_bounds__(NT) void k_pass2(const float* __restrict__ coords,
        const float* __restrict__ pk2, float* __restrict__ part, int N, int K) {
    int n = blockIdx.x*NT + threadIdx.x;
    int s = blockIdx.y;
    int ksplit = gridDim.y;
    int KC = (K + ksplit - 1)/ksplit;
    int k0 = s*KC, k1 = min(K, k0+KC);
    bool act = n < N;
    float rx=0.f,ry=0.f,rz=0.f;
    if (act){ rx=coords[3*n]; ry=coords[3*n+1]; rz=coords[3*n+2]; }
    float pot=0.f,fx=0.f,fy=0.f,fz=0.f;
    #pragma unroll 2
    for (int k=k0;k<k1;++k) {
        const float* o = pk2 + 8*(size_t)k;   // uniform address -> s_load
        float ax=o[0],ay=o[1],az=o[2],srg=o[3],sig=o[4];
        float u = ax*rx + ay*ry + az*rz;
        float ss,cc; sincos2pi(u,ss,cc);
        pot += srg*cc + sig*ss;
        float kim = srg*ss - sig*cc;
        fx += kim*ax; fy += kim*ay; fz += kim*az;
    }
    if (act) {
        int SP = ksplit;
        part[(size_t)(0*SP+s)*N+n]=pot;
        part[(size_t)(1*SP+s)*N+n]=fx;
        part[(size_t)(2*SP+s)*N+n]=fy;
        part[(size_t)(3*SP+s)*N+n]=fz;
    }
}

// ---------------- finalize potential + field
__global__ void k_fin(const float* __restrict__ part, const float* __restrict__ q,
                      const float* __restrict__ p, const float* __restrict__ head,
                      float* __restrict__ out, int N, int ksplit) {
    int n = blockIdx.x*NT + threadIdx.x;
    if (n >= N) return;
    float sp=0.f,sfx=0.f,sfy=0.f,sfz=0.f;
    for (int s=0;s<ksplit;++s){
        sp  += part[(size_t)(0*ksplit+s)*N+n];
        sfx += part[(size_t)(1*ksplit+s)*N+n];
        sfy += part[(size_t)(2*ksplit+s)*N+n];
        sfz += part[(size_t)(3*ksplit+s)*N+n];
    }
    float V = head[9];
    float arpi = ALPHA_F/sqrtf(PI_F);
    float a2 = ALPHA_F*ALPHA_F;
    out[1+n] = (2.0f/(PI_F*V))*sp - 2.0f*arpi*q[n];
    float cf = 4.0f/V;
    float cp2 = arpi*(4.0f*a2/3.0f);
    out[1+N+3*n+0] = cf*sfx + cp2*p[3*n+0];
    out[1+N+3*n+1] = cf*sfy + cp2*p[3*n+1];
    out[1+N+3*n+2] = cf*sfz + cp2*p[3*n+2];
}

extern "C" void kernel_launch(void* const* d_in, const int* in_sizes, int n_in,
                              void* d_out, int out_size, void* d_ws, size_t ws_size,
                              hipStream_t stream) {
    const float* coords = (const float*)d_in[0];
    const float* box    = (const float*)d_in[1];
    const float* q      = (const float*)d_in[2];
    const float* p      = (const float*)d_in[3];
    const float* t      = (const float*)d_in[4];
    const float* kvecs  = (const float*)d_in[5];
    int N = in_sizes[0]/3;
    int K = in_sizes[5]/3;
    float* ws = (float*)d_ws;
    size_t ws_floats = ws_size / 4;

    int asplit = 32, ksplit = 32;
    // shrink splits if the workspace is small (partials are the bulk)
    auto need = [&](int as, int ks)->size_t {
        return 16 + 16*(size_t)K + 8*(size_t)K + 16*(size_t)N
             + 2*(size_t)as*K + 16 + 256 + 4*(size_t)ks*N;
    };
    while (need(asplit,ksplit) > ws_floats && (asplit>2 || ksplit>2)) {
        if (asplit>2) asplit >>= 1;
        if (ksplit>2) ksplit >>= 1;
    }

    size_t off = 0;
    float* head   = ws + off; off += 16;
    float* pk1    = ws + off; off += 16*(size_t)K;
    float* pk2    = ws + off; off += 8*(size_t)K;
    float* atom16 = ws + off; off += 16*(size_t)N;
    float* psr    = ws + off; off += (size_t)asplit*K;
    float* psi    = ws + off; off += (size_t)asplit*K;
    float* selfs  = ws + off; off += 16;
    float* eblk   = ws + off; off += 256;
    float* part   = ws + off; off += 4*(size_t)ksplit*N;

    int kb = (K + NT - 1)/NT;
    int nb = (N + NT - 1)/NT;

    k_box  <<<1, 64, 0, stream>>>(box, head);
    k_kvec <<<kb, NT, 0, stream>>>(kvecs, head, pk1, pk2, K);
    k_atoms<<<nb, NT, 0, stream>>>(coords, q, p, t, atom16, N);
    k_self <<<1, NT, 0, stream>>>(q, p, t, selfs, N);

    dim3 g1(kb, asplit);
    k_pass1<<<g1, NT, 0, stream>>>(pk1, atom16, psr, psi, N, K);
    k_reduce1<<<kb, NT, 0, stream>>>(pk1, psr, psi, pk2, eblk, K, asplit);
    k_energy<<<1, 64, 0, stream>>>(eblk, kb, selfs, head, (float*)d_out);

    dim3 g2(nb, ksplit);
    k_pass2<<<g2, NT, 0, stream>>>(coords, pk2, part, N, K);
    k_fin  <<<nb, NT, 0, stream>>>(part, q, p, head, (float*)d_out, N, ksplit);
}

// Round 2
// 141.287 us; speedup vs baseline: 1.1743x; 1.1743x over previous
//
#include <hip/hip_runtime.h>

#define PI_F      3.14159265358979f
#define TWO_PI_F  6.28318530717959f
#define ALPHA_F   0.3f
#define NT        256

// sin/cos of 2*pi*u using the hardware trig units (input in revolutions).
__device__ __forceinline__ void sincos2pi(float u, float& s, float& c) {
#if __has_builtin(__builtin_amdgcn_fractf)
    float uf = __builtin_amdgcn_fractf(u);
#else
    float uf = u - floorf(u);
#endif
    asm("v_sin_f32 %0, %1" : "=v"(s) : "v"(uf));
    asm("v_cos_f32 %0, %1" : "=v"(c) : "v"(uf));
}

// 3x3 inverse (row-major), returns det.
__device__ __forceinline__ float inv3(const float* b, float* inv) {
    float c00 = b[4]*b[8] - b[5]*b[7];
    float c01 = b[2]*b[7] - b[1]*b[8];
    float c02 = b[1]*b[5] - b[2]*b[4];
    float c10 = b[5]*b[6] - b[3]*b[8];
    float c11 = b[0]*b[8] - b[2]*b[6];
    float c12 = b[2]*b[3] - b[0]*b[5];
    float c20 = b[3]*b[7] - b[4]*b[6];
    float c21 = b[1]*b[6] - b[0]*b[7];
    float c22 = b[0]*b[4] - b[1]*b[3];
    float det = b[0]*c00 + b[1]*c10 + b[2]*c20;
    float id = 1.0f/det;
    inv[0]=c00*id; inv[1]=c01*id; inv[2]=c02*id;
    inv[3]=c10*id; inv[4]=c11*id; inv[5]=c12*id;
    inv[6]=c20*id; inv[7]=c21*id; inv[8]=c22*id;
    return det;
}

// ---------------- fused prep:
// blocks [0,kb): k-vector prep -> pk1[k][16], pk2[k][8]
// blocks [kb,kb+nb): atom prep -> atom16[n][16], plus per-block self-energy partials
__global__ __launch_bounds__(NT) void k_prep(
        const float* __restrict__ box, const float* __restrict__ kvecs,
        const float* __restrict__ coords, const float* __restrict__ q,
        const float* __restrict__ p, const float* __restrict__ t,
        float* __restrict__ pk1, float* __restrict__ pk2,
        float* __restrict__ atom16, float* __restrict__ selfp,
        int K, int N, int kb) {
    if ((int)blockIdx.x < kb) {
        int k = blockIdx.x*NT + threadIdx.x;
        if (k >= K) return;
        float bi[9]; float b[9];
        #pragma unroll
        for (int j=0;j<9;++j) b[j]=box[j];
        inv3(b, bi);
        float kx=kvecs[3*k], ky=kvecs[3*k+1], kz=kvecs[3*k+2];
        float ax = kx*bi[0] + ky*bi[3] + kz*bi[6];
        float ay = kx*bi[1] + ky*bi[4] + kz*bi[7];
        float az = kx*bi[2] + ky*bi[5] + kz*bi[8];
        float ksq = ax*ax + ay*ay + az*az;
        float g = expf(-PI_F*PI_F*ksq/(ALPHA_F*ALPHA_F)) / ksq;
        float* o = pk1 + 16*(size_t)k;
        o[0]=ax; o[1]=ay; o[2]=az;
        o[3]=ax*ax; o[4]=ay*ay; o[5]=az*az;
        o[6]=ax*ay; o[7]=ax*az; o[8]=ay*az;
        o[9]=g; o[10]=0.f; o[11]=0.f; o[12]=0.f; o[13]=0.f; o[14]=0.f; o[15]=0.f;
        float* o2 = pk2 + 8*(size_t)k;
        o2[0]=ax; o2[1]=ay; o2[2]=az; o2[3]=0.f; o2[4]=0.f; o2[5]=0.f; o2[6]=0.f; o2[7]=0.f;
    } else {
        int blk = blockIdx.x - kb;
        int n = blk*NT + threadIdx.x;
        float sq=0.f, sp=0.f, st=0.f;
        if (n < N) {
            const float c1 = TWO_PI_F*TWO_PI_F/3.0f;
            const float* tn = t + 9*(size_t)n;
            float* o = atom16 + 16*(size_t)n;
            o[0]=coords[3*n]; o[1]=coords[3*n+1]; o[2]=coords[3*n+2];
            float qq = q[n];
            o[3]=qq;
            float p0=p[3*n],p1=p[3*n+1],p2=p[3*n+2];
            o[4]=TWO_PI_F*p0; o[5]=TWO_PI_F*p1; o[6]=TWO_PI_F*p2;
            float t0=tn[0],t1=tn[1],t2=tn[2],t3=tn[3],t4=tn[4],
                  t5=tn[5],t6=tn[6],t7=tn[7],t8=tn[8];
            o[7]=c1*t0; o[8]=c1*t4; o[9]=c1*t8;
            o[10]=c1*(t1+t3); o[11]=c1*(t2+t6); o[12]=c1*(t5+t7);
            o[13]=0.f; o[14]=0.f; o[15]=0.f;
            sq = qq*qq;
            sp = p0*p0 + p1*p1 + p2*p2;
            st = t0*t0+t1*t1+t2*t2+t3*t3+t4*t4+t5*t5+t6*t6+t7*t7+t8*t8;
        }
        __shared__ float lds[3][4];
        int lane = threadIdx.x & 63, w = threadIdx.x >> 6;
        for (int o=32;o;o>>=1) {
            sq += __shfl_down(sq,o,64); sp += __shfl_down(sp,o,64); st += __shfl_down(st,o,64);
        }
        if (lane==0){ lds[0][w]=sq; lds[1][w]=sp; lds[2][w]=st; }
        __syncthreads();
        if (threadIdx.x==0){
            selfp[4*blk+0]=lds[0][0]+lds[0][1]+lds[0][2]+lds[0][3];
            selfp[4*blk+1]=lds[1][0]+lds[1][1]+lds[1][2]+lds[1][3];
            selfp[4*blk+2]=lds[2][0]+lds[2][1]+lds[2][2]+lds[2][3];
        }
    }
}

// ---------------- pass 1: lane = k, loop atoms (uniform scalar loads). partials over atom-splits.
__global__ __launch_bounds__(NT) void k_pass1(const float* __restrict__ pk1,
        const float* __restrict__ atom16, float* __restrict__ psr, float* __restrict__ psi,
        int N, int K) {
    int k = blockIdx.x*NT + threadIdx.x;
    int s = blockIdx.y;
    int nsplit = gridDim.y;
    int AC = (N + nsplit - 1)/nsplit;
    int n0 = s*AC, n1 = min(N, n0+AC);
    float ax=0,ay=0,az=0,axx=0,ayy=0,azz=0,axy=0,axz=0,ayz=0;
    if (k < K) {
        const float* o = pk1 + 16*(size_t)k;
        ax=o[0]; ay=o[1]; az=o[2]; axx=o[3]; ayy=o[4]; azz=o[5];
        axy=o[6]; axz=o[7]; ayz=o[8];
    }
    float sr=0.f, si=0.f;
    #pragma unroll 4
    for (int n = n0; n < n1; ++n) {
        const float* an = atom16 + 16*(size_t)n;   // uniform address -> s_load
        float rx=an[0], ry=an[1], rz=an[2], qn=an[3];
        float px=an[4], py=an[5], pz=an[6];
        float sxx=an[7], syy=an[8], szz=an[9], sxy=an[10], sxz=an[11], syz=an[12];
        float u = ax*rx + ay*ry + az*rz;
        float ss, cc; sincos2pi(u, ss, cc);
        float quad = axx*sxx + ayy*syy + azz*szz + axy*sxy + axz*sxz + ayz*syz;
        float Lr = qn - quad;
        float Li = ax*px + ay*py + az*pz;
        sr += cc*Lr - ss*Li;
        si += cc*Li + ss*Lr;
    }
    if (k < K) { psr[(size_t)s*K + k] = sr; psi[(size_t)s*K + k] = si; }
}

// ---------------- reduce pass-1 partials -> SrG/SiG in pk2, per-block energy partials
__global__ __launch_bounds__(NT) void k_reduce1(const float* __restrict__ pk1,
                          const float* __restrict__ psr,
                          const float* __restrict__ psi, float* __restrict__ pk2,
                          float* __restrict__ eblk, int K, int nsplit) {
    int k = blockIdx.x*NT + threadIdx.x;
    float ek = 0.f;
    if (k < K) {
        float sr=0.f, si=0.f;
        for (int s=0;s<nsplit;++s){ sr += psr[(size_t)s*K+k]; si += psi[(size_t)s*K+k]; }
        float g = pk1[16*(size_t)k + 9];
        float srg = g*sr, sig = g*si;
        pk2[8*(size_t)k+3] = srg;
        pk2[8*(size_t)k+4] = sig;
        ek = srg*sr + sig*si;
    }
    __shared__ float lds[4];
    int lane = threadIdx.x & 63, w = threadIdx.x >> 6;
    for (int o=32;o;o>>=1) ek += __shfl_down(ek,o,64);
    if (lane==0) lds[w]=ek;
    __syncthreads();
    if (threadIdx.x==0) eblk[blockIdx.x] = lds[0]+lds[1]+lds[2]+lds[3];
}

// ---------------- energy final (also sums self-energy partials)
__global__ void k_energy(const float* __restrict__ eblk, int nblk,
                         const float* __restrict__ selfp, int nself,
                         const float* __restrict__ box,
                         float* __restrict__ out) {
    int lane = threadIdx.x;
    float e=0.f, sq=0.f, sp=0.f, st=0.f;
    for (int i=lane;i<nblk;i+=64) e += eblk[i];
    for (int i=lane;i<nself;i+=64){ sq+=selfp[4*i]; sp+=selfp[4*i+1]; st+=selfp[4*i+2]; }
    for (int o=32;o;o>>=1) {
        e += __shfl_down(e,o,64); sq += __shfl_down(sq,o,64);
        sp += __shfl_down(sp,o,64); st += __shfl_down(st,o,64);
    }
    if (lane==0) {
        float b[9];
        #pragma unroll
        for (int j=0;j<9;++j) b[j]=box[j];
        float V = b[0]*(b[4]*b[8]-b[5]*b[7]) + b[1]*(b[5]*b[6]-b[3]*b[8]) + b[2]*(b[3]*b[7]-b[4]*b[6]);
        float arpi = ALPHA_F/sqrtf(PI_F);
        float a2 = ALPHA_F*ALPHA_F;
        float energy = e/(PI_F*V)
                     - arpi*sq
                     - arpi*(2.0f*a2/3.0f)*sp
                     - arpi*(8.0f*a2*a2/45.0f)*st;
        out[0] = energy;
    }
}

// ---------------- pass 2: lane = atom, loop k (uniform scalar loads). partials over k-splits.
__global__ __launch_bounds__(NT) void k_pass2(const float* __restrict__ coords,
        const float* __restrict__ pk2, float* __restrict__ part, int N, int K) {
    int n = blockIdx.x*NT + threadIdx.x;
    int s = blockIdx.y;
    int ksplit = gridDim.y;
    int KC = (K + ksplit - 1)/ksplit;
    int k0 = s*KC, k1 = min(K, k0+KC);
    bool act = n < N;
    float rx=0.f,ry=0.f,rz=0.f;
    if (act){ rx=coords[3*n]; ry=coords[3*n+1]; rz=coords[3*n+2]; }
    float pot=0.f,fx=0.f,fy=0.f,fz=0.f;
    #pragma unroll 4
    for (int k=k0;k<k1;++k) {
        const float* o = pk2 + 8*(size_t)k;   // uniform address -> s_load
        float ax=o[0],ay=o[1],az=o[2],srg=o[3],sig=o[4];
        float u = ax*rx + ay*ry + az*rz;
        float ss,cc; sincos2pi(u,ss,cc);
        pot += srg*cc + sig*ss;
        float kim = srg*ss - sig*cc;
        fx += kim*ax; fy += kim*ay; fz += kim*az;
    }
    if (act) {
        int SP = ksplit;
        part[(size_t)(0*SP+s)*N+n]=pot;
        part[(size_t)(1*SP+s)*N+n]=fx;
        part[(size_t)(2*SP+s)*N+n]=fy;
        part[(size_t)(3*SP+s)*N+n]=fz;
    }
}

// ---------------- finalize potential + field
__global__ __launch_bounds__(NT) void k_fin(const float* __restrict__ part,
                      const float* __restrict__ q,
                      const float* __restrict__ p, const float* __restrict__ box,
                      float* __restrict__ out, int N, int ksplit) {
    int n = blockIdx.x*NT + threadIdx.x;
    if (n >= N) return;
    float sp=0.f,sfx=0.f,sfy=0.f,sfz=0.f;
    for (int s=0;s<ksplit;++s){
        sp  += part[(size_t)(0*ksplit+s)*N+n];
        sfx += part[(size_t)(1*ksplit+s)*N+n];
        sfy += part[(size_t)(2*ksplit+s)*N+n];
        sfz += part[(size_t)(3*ksplit+s)*N+n];
    }
    float b[9];
    #pragma unroll
    for (int j=0;j<9;++j) b[j]=box[j];
    float V = b[0]*(b[4]*b[8]-b[5]*b[7]) + b[1]*(b[5]*b[6]-b[3]*b[8]) + b[2]*(b[3]*b[7]-b[4]*b[6]);
    float arpi = ALPHA_F/sqrtf(PI_F);
    float a2 = ALPHA_F*ALPHA_F;
    out[1+n] = (2.0f/(PI_F*V))*sp - 2.0f*arpi*q[n];
    float cf = 4.0f/V;
    float cp2 = arpi*(4.0f*a2/3.0f);
    out[1+N+3*n+0] = cf*sfx + cp2*p[3*n+0];
    out[1+N+3*n+1] = cf*sfy + cp2*p[3*n+1];
    out[1+N+3*n+2] = cf*sfz + cp2*p[3*n+2];
}

extern "C" void kernel_launch(void* const* d_in, const int* in_sizes, int n_in,
                              void* d_out, int out_size, void* d_ws, size_t ws_size,
                              hipStream_t stream) {
    const float* coords = (const float*)d_in[0];
    const float* box    = (const float*)d_in[1];
    const float* q      = (const float*)d_in[2];
    const float* p      = (const float*)d_in[3];
    const float* t      = (const float*)d_in[4];
    const float* kvecs  = (const float*)d_in[5];
    int N = in_sizes[0]/3;
    int K = in_sizes[5]/3;
    float* ws = (float*)d_ws;
    size_t ws_floats = ws_size / 4;

    int kb = (K + NT - 1)/NT;
    int nb = (N + NT - 1)/NT;

    int asplit = 64, ksplit = 80;
    auto need = [&](int as, int ks)->size_t {
        return 16*(size_t)K + 8*(size_t)K + 16*(size_t)N
             + 2*(size_t)as*K + 4*(size_t)nb + 256 + (size_t)kb
             + 4*(size_t)ks*N + 64;
    };
    while (need(asplit,ksplit) > ws_floats && (asplit>2 || ksplit>2)) {
        if (asplit>2) asplit >>= 1;
        if (ksplit>2) ksplit >>= 1;
    }

    size_t off = 0;
    float* pk1    = ws + off; off += 16*(size_t)K;
    float* pk2    = ws + off; off += 8*(size_t)K;
    float* atom16 = ws + off; off += 16*(size_t)N;
    float* psr    = ws + off; off += (size_t)asplit*K;
    float* psi    = ws + off; off += (size_t)asplit*K;
    float* selfp  = ws + off; off += 4*(size_t)nb + 256;
    float* eblk   = ws + off; off += (size_t)kb + 64;
    float* part   = ws + off; off += 4*(size_t)ksplit*N;

    k_prep<<<kb + nb, NT, 0, stream>>>(box, kvecs, coords, q, p, t,
                                       pk1, pk2, atom16, selfp, K, N, kb);

    dim3 g1(kb, asplit);
    k_pass1<<<g1, NT, 0, stream>>>(pk1, atom16, psr, psi, N, K);
    k_reduce1<<<kb, NT, 0, stream>>>(pk1, psr, psi, pk2, eblk, K, asplit);
    k_energy<<<1, 64, 0, stream>>>(eblk, kb, selfp, nb, box, (float*)d_out);

    dim3 g2(nb, ksplit);
    k_pass2<<<g2, NT, 0, stream>>>(coords, pk2, part, N, K);
    k_fin  <<<nb, NT, 0, stream>>>(part, q, p, box, (float*)d_out, N, ksplit);
}

// Round 3
// 118.234 us; speedup vs baseline: 1.4033x; 1.1950x over previous
//
#include <hip/hip_runtime.h>

#define PI_F      3.14159265358979f
#define TWO_PI_F  6.28318530717959f
#define ALPHA_F   0.3f
#define NT        256

// sin/cos of 2*pi*u using the hardware trig units (input in revolutions).
__device__ __forceinline__ void sincos2pi(float u, float& s, float& c) {
#if __has_builtin(__builtin_amdgcn_fractf)
    float uf = __builtin_amdgcn_fractf(u);
#else
    float uf = u - floorf(u);
#endif
    asm("v_sin_f32 %0, %1" : "=v"(s) : "v"(uf));
    asm("v_cos_f32 %0, %1" : "=v"(c) : "v"(uf));
}

// 3x3 inverse (row-major), returns det.
__device__ __forceinline__ float inv3(const float* b, float* inv) {
    float c00 = b[4]*b[8] - b[5]*b[7];
    float c01 = b[2]*b[7] - b[1]*b[8];
    float c02 = b[1]*b[5] - b[2]*b[4];
    float c10 = b[5]*b[6] - b[3]*b[8];
    float c11 = b[0]*b[8] - b[2]*b[6];
    float c12 = b[2]*b[3] - b[0]*b[5];
    float c20 = b[3]*b[7] - b[4]*b[6];
    float c21 = b[1]*b[6] - b[0]*b[7];
    float c22 = b[0]*b[4] - b[1]*b[3];
    float det = b[0]*c00 + b[1]*c10 + b[2]*c20;
    float id = 1.0f/det;
    inv[0]=c00*id; inv[1]=c01*id; inv[2]=c02*id;
    inv[3]=c10*id; inv[4]=c11*id; inv[5]=c12*id;
    inv[6]=c20*id; inv[7]=c21*id; inv[8]=c22*id;
    return det;
}

// ---------------- fused prep:
// blocks [0,kb): k-vector prep -> pk1[k][16] = {ax,ay,az,g, axx,ayy,azz,axy, axz,ayz,..}
//                                 pk2[k][8]  = {ax,ay,az,(SrG),(SiG),..}
// blocks [kb,kb+nb): atom prep -> atom16[n][16] = {rx,ry,rz,q, px,py,pz,sxx, syy,szz,sxy,sxz, syz,..}
//                                 + per-block self-energy partials
__global__ __launch_bounds__(NT) void k_prep(
        const float* __restrict__ box, const float* __restrict__ kvecs,
        const float* __restrict__ coords, const float* __restrict__ q,
        const float* __restrict__ p, const float* __restrict__ t,
        float* __restrict__ pk1, float* __restrict__ pk2,
        float* __restrict__ atom16, float* __restrict__ selfp,
        int K, int N, int kb) {
    if ((int)blockIdx.x < kb) {
        int k = blockIdx.x*NT + threadIdx.x;
        if (k >= K) return;
        float bi[9]; float b[9];
        #pragma unroll
        for (int j=0;j<9;++j) b[j]=box[j];
        inv3(b, bi);
        float kx=kvecs[3*k], ky=kvecs[3*k+1], kz=kvecs[3*k+2];
        float ax = kx*bi[0] + ky*bi[3] + kz*bi[6];
        float ay = kx*bi[1] + ky*bi[4] + kz*bi[7];
        float az = kx*bi[2] + ky*bi[5] + kz*bi[8];
        float ksq = ax*ax + ay*ay + az*az;
        float g = expf(-PI_F*PI_F*ksq/(ALPHA_F*ALPHA_F)) / ksq;
        float* o = pk1 + 16*(size_t)k;
        o[0]=ax; o[1]=ay; o[2]=az; o[3]=g;
        o[4]=ax*ax; o[5]=ay*ay; o[6]=az*az; o[7]=ax*ay;
        o[8]=ax*az; o[9]=ay*az; o[10]=0.f; o[11]=0.f;
        o[12]=0.f; o[13]=0.f; o[14]=0.f; o[15]=0.f;
        float* o2 = pk2 + 8*(size_t)k;
        o2[0]=ax; o2[1]=ay; o2[2]=az; o2[3]=0.f; o2[4]=0.f; o2[5]=0.f; o2[6]=0.f; o2[7]=0.f;
    } else {
        int blk = blockIdx.x - kb;
        int n = blk*NT + threadIdx.x;
        float sq=0.f, sp=0.f, st=0.f;
        if (n < N) {
            const float c1 = TWO_PI_F*TWO_PI_F/3.0f;
            const float* tn = t + 9*(size_t)n;
            float* o = atom16 + 16*(size_t)n;
            o[0]=coords[3*n]; o[1]=coords[3*n+1]; o[2]=coords[3*n+2];
            float qq = q[n];
            o[3]=qq;
            float p0=p[3*n],p1=p[3*n+1],p2=p[3*n+2];
            o[4]=TWO_PI_F*p0; o[5]=TWO_PI_F*p1; o[6]=TWO_PI_F*p2;
            float t0=tn[0],t1=tn[1],t2=tn[2],t3=tn[3],t4=tn[4],
                  t5=tn[5],t6=tn[6],t7=tn[7],t8=tn[8];
            o[7]=c1*t0;
            o[8]=c1*t4; o[9]=c1*t8; o[10]=c1*(t1+t3); o[11]=c1*(t2+t6);
            o[12]=c1*(t5+t7); o[13]=0.f; o[14]=0.f; o[15]=0.f;
            sq = qq*qq;
            sp = p0*p0 + p1*p1 + p2*p2;
            st = t0*t0+t1*t1+t2*t2+t3*t3+t4*t4+t5*t5+t6*t6+t7*t7+t8*t8;
        }
        __shared__ float lds[3][4];
        int lane = threadIdx.x & 63, w = threadIdx.x >> 6;
        for (int o=32;o;o>>=1) {
            sq += __shfl_down(sq,o,64); sp += __shfl_down(sp,o,64); st += __shfl_down(st,o,64);
        }
        if (lane==0){ lds[0][w]=sq; lds[1][w]=sp; lds[2][w]=st; }
        __syncthreads();
        if (threadIdx.x==0){
            selfp[4*blk+0]=lds[0][0]+lds[0][1]+lds[0][2]+lds[0][3];
            selfp[4*blk+1]=lds[1][0]+lds[1][1]+lds[1][2]+lds[1][3];
            selfp[4*blk+2]=lds[2][0]+lds[2][1]+lds[2][2]+lds[2][3];
        }
    }
}

// ---------------- pass 1: lane = k, loop atoms (uniform scalar loads, 2-deep pipeline).
__global__ __launch_bounds__(NT) void k_pass1(const float* __restrict__ pk1,
        const float* __restrict__ atom16, float* __restrict__ psr, float* __restrict__ psi,
        int N, int K) {
    int k = blockIdx.x*NT + threadIdx.x;
    int s = blockIdx.y;
    int nsplit = gridDim.y;
    int AC = (N + nsplit - 1)/nsplit;
    int n0 = s*AC, n1 = min(N, n0+AC);
    float ax=0,ay=0,az=0,axx=0,ayy=0,azz=0,axy=0,axz=0,ayz=0;
    if (k < K) {
        const float* o = pk1 + 16*(size_t)k;
        ax=o[0]; ay=o[1]; az=o[2]; axx=o[4]; ayy=o[5]; azz=o[6];
        axy=o[7]; axz=o[8]; ayz=o[9];
    }
    const float4* ab = (const float4*)atom16;
    float sr=0.f, si=0.f;
    // prologue: load record n0 (pad guarantees n0 valid read even if n0>=n1)
    float4 A0 = ab[4*(size_t)n0+0];
    float4 A1 = ab[4*(size_t)n0+1];
    float4 A2 = ab[4*(size_t)n0+2];
    float4 A3 = ab[4*(size_t)n0+3];
    #pragma unroll 2
    for (int n = n0; n < n1; ++n) {
        // prefetch next record while computing current (pad allows n1 read)
        float4 B0 = ab[4*(size_t)(n+1)+0];
        float4 B1 = ab[4*(size_t)(n+1)+1];
        float4 B2 = ab[4*(size_t)(n+1)+2];
        float4 B3 = ab[4*(size_t)(n+1)+3];
        float u = ax*A0.x + ay*A0.y + az*A0.z;
        float ss, cc; sincos2pi(u, ss, cc);
        float quad = axx*A1.w + ayy*A2.x + azz*A2.y + axy*A2.z + axz*A2.w + ayz*A3.x;
        float Lr = A0.w - quad;
        float Li = ax*A1.x + ay*A1.y + az*A1.z;
        sr += cc*Lr - ss*Li;
        si += cc*Li + ss*Lr;
        A0=B0; A1=B1; A2=B2; A3=B3;
    }
    if (k < K) { psr[(size_t)s*K + k] = sr; psi[(size_t)s*K + k] = si; }
}

// ---------------- reduce pass-1 partials -> SrG/SiG in pk2, per-block energy partials
__global__ __launch_bounds__(NT) void k_reduce1(const float* __restrict__ pk1,
                          const float* __restrict__ psr,
                          const float* __restrict__ psi, float* __restrict__ pk2,
                          float* __restrict__ eblk, int K, int nsplit) {
    int k = blockIdx.x*NT + threadIdx.x;
    float ek = 0.f;
    if (k < K) {
        float sr=0.f, si=0.f;
        #pragma unroll 4
        for (int s=0;s<nsplit;++s){ sr += psr[(size_t)s*K+k]; si += psi[(size_t)s*K+k]; }
        float g = pk1[16*(size_t)k + 3];
        float srg = g*sr, sig = g*si;
        pk2[8*(size_t)k+3] = srg;
        pk2[8*(size_t)k+4] = sig;
        ek = srg*sr + sig*si;
    }
    __shared__ float lds[4];
    int lane = threadIdx.x & 63, w = threadIdx.x >> 6;
    for (int o=32;o;o>>=1) ek += __shfl_down(ek,o,64);
    if (lane==0) lds[w]=ek;
    __syncthreads();
    if (threadIdx.x==0) eblk[blockIdx.x] = lds[0]+lds[1]+lds[2]+lds[3];
}

// ---------------- pass 2: lane = atom, loop k (uniform scalar loads, 2-deep pipeline).
__global__ __launch_bounds__(NT) void k_pass2(const float* __restrict__ coords,
        const float* __restrict__ pk2, float* __restrict__ part, int N, int K) {
    int n = blockIdx.x*NT + threadIdx.x;
    int s = blockIdx.y;
    int ksplit = gridDim.y;
    int KC = (K + ksplit - 1)/ksplit;
    int k0 = s*KC, k1 = min(K, k0+KC);
    bool act = n < N;
    float rx=0.f,ry=0.f,rz=0.f;
    if (act){ rx=coords[3*n]; ry=coords[3*n+1]; rz=coords[3*n+2]; }
    const float4* kbuf = (const float4*)pk2;
    float pot=0.f,fx=0.f,fy=0.f,fz=0.f;
    float4 A0 = kbuf[2*(size_t)k0+0];
    float4 A1 = kbuf[2*(size_t)k0+1];
    #pragma unroll 2
    for (int k=k0;k<k1;++k) {
        float4 B0 = kbuf[2*(size_t)(k+1)+0];
        float4 B1 = kbuf[2*(size_t)(k+1)+1];
        float u = A0.x*rx + A0.y*ry + A0.z*rz;
        float ss,cc; sincos2pi(u,ss,cc);
        float srg=A0.w, sig=A1.x;
        pot += srg*cc + sig*ss;
        float kim = srg*ss - sig*cc;
        fx += kim*A0.x; fy += kim*A0.y; fz += kim*A0.z;
        A0=B0; A1=B1;
    }
    if (act) {
        int SP = ksplit;
        part[(size_t)(0*SP+s)*N+n]=pot;
        part[(size_t)(1*SP+s)*N+n]=fx;
        part[(size_t)(2*SP+s)*N+n]=fy;
        part[(size_t)(3*SP+s)*N+n]=fz;
    }
}

// ---------------- finalize potential + field; block 0 finalizes energy
__global__ __launch_bounds__(NT) void k_fin(const float* __restrict__ part,
                      const float* __restrict__ q,
                      const float* __restrict__ p, const float* __restrict__ box,
                      const float* __restrict__ eblk, int nblk,
                      const float* __restrict__ selfp, int nself,
                      float* __restrict__ out, int N, int ksplit) {
    float b[9];
    #pragma unroll
    for (int j=0;j<9;++j) b[j]=box[j];
    float V = b[0]*(b[4]*b[8]-b[5]*b[7]) + b[1]*(b[5]*b[6]-b[3]*b[8]) + b[2]*(b[3]*b[7]-b[4]*b[6]);
    float arpi = ALPHA_F/sqrtf(PI_F);
    float a2 = ALPHA_F*ALPHA_F;
    if (blockIdx.x == 0) {
        // energy finalization on one wave
        int lane = threadIdx.x;
        if (lane >= 64) return;
        float e=0.f, sq=0.f, sp=0.f, st=0.f;
        for (int i=lane;i<nblk;i+=64) e += eblk[i];
        for (int i=lane;i<nself;i+=64){ sq+=selfp[4*i]; sp+=selfp[4*i+1]; st+=selfp[4*i+2]; }
        for (int o=32;o;o>>=1) {
            e += __shfl_down(e,o,64); sq += __shfl_down(sq,o,64);
            sp += __shfl_down(sp,o,64); st += __shfl_down(st,o,64);
        }
        if (lane==0) {
            out[0] = e/(PI_F*V) - arpi*sq - arpi*(2.0f*a2/3.0f)*sp
                   - arpi*(8.0f*a2*a2/45.0f)*st;
        }
        return;
    }
    int n = (blockIdx.x-1)*NT + threadIdx.x;
    if (n >= N) return;
    float sp=0.f,sfx=0.f,sfy=0.f,sfz=0.f;
    #pragma unroll 4
    for (int s=0;s<ksplit;++s){
        sp  += part[(size_t)(0*ksplit+s)*N+n];
        sfx += part[(size_t)(1*ksplit+s)*N+n];
        sfy += part[(size_t)(2*ksplit+s)*N+n];
        sfz += part[(size_t)(3*ksplit+s)*N+n];
    }
    out[1+n] = (2.0f/(PI_F*V))*sp - 2.0f*arpi*q[n];
    float cf = 4.0f/V;
    float cp2 = arpi*(4.0f*a2/3.0f);
    out[1+N+3*n+0] = cf*sfx + cp2*p[3*n+0];
    out[1+N+3*n+1] = cf*sfy + cp2*p[3*n+1];
    out[1+N+3*n+2] = cf*sfz + cp2*p[3*n+2];
}

extern "C" void kernel_launch(void* const* d_in, const int* in_sizes, int n_in,
                              void* d_out, int out_size, void* d_ws, size_t ws_size,
                              hipStream_t stream) {
    const float* coords = (const float*)d_in[0];
    const float* box    = (const float*)d_in[1];
    const float* q      = (const float*)d_in[2];
    const float* p      = (const float*)d_in[3];
    const float* t      = (const float*)d_in[4];
    const float* kvecs  = (const float*)d_in[5];
    int N = in_sizes[0]/3;
    int K = in_sizes[5]/3;
    float* ws = (float*)d_ws;
    size_t ws_floats = ws_size / 4;

    int kb = (K + NT - 1)/NT;
    int nb = (N + NT - 1)/NT;

    int asplit = 128, ksplit = 128;
    auto need = [&](int as, int ks)->size_t {
        return 16*(size_t)K + 8*(size_t)K + 8 /*pk2 pad*/ + 16*(size_t)N + 16 /*atom pad*/
             + 2*(size_t)as*K + 4*(size_t)nb + 256 + (size_t)kb
             + 4*(size_t)ks*N + 64;
    };
    while (need(asplit,ksplit) > ws_floats && (asplit>2 || ksplit>2)) {
        if (asplit>2) asplit >>= 1;
        if (ksplit>2) ksplit >>= 1;
    }

    size_t off = 0;
    float* pk1    = ws + off; off += 16*(size_t)K;
    float* pk2    = ws + off; off += 8*(size_t)K + 8;      // +1 pad record
    float* atom16 = ws + off; off += 16*(size_t)N + 16;    // +1 pad record
    float* psr    = ws + off; off += (size_t)asplit*K;
    float* psi    = ws + off; off += (size_t)asplit*K;
    float* selfp  = ws + off; off += 4*(size_t)nb + 256;
    float* eblk   = ws + off; off += (size_t)kb + 64;
    float* part   = ws + off; off += 4*(size_t)ksplit*N;

    k_prep<<<kb + nb, NT, 0, stream>>>(box, kvecs, coords, q, p, t,
                                       pk1, pk2, atom16, selfp, K, N, kb);

    dim3 g1(kb, asplit);
    k_pass1<<<g1, NT, 0, stream>>>(pk1, atom16, psr, psi, N, K);
    k_reduce1<<<kb, NT, 0, stream>>>(pk1, psr, psi, pk2, eblk, K, asplit);

    dim3 g2(nb, ksplit);
    k_pass2<<<g2, NT, 0, stream>>>(coords, pk2, part, N, K);
    k_fin  <<<nb + 1, NT, 0, stream>>>(part, q, p, box, eblk, kb, selfp, nb,
                                       (float*)d_out, N, ksplit);
}

// Round 4
// 116.815 us; speedup vs baseline: 1.4203x; 1.0121x over previous
//
#include <hip/hip_runtime.h>

#define PI_F      3.14159265358979f
#define TWO_PI_F  6.28318530717959f
#define ALPHA_F   0.3f
#define NT        256
#define ACHUNK    80    // atoms staged per pass-1 block
#define KCHUNK    84    // k-records staged per pass-2 block

// sin/cos of 2*pi*u using the hardware trig units (input in revolutions).
__device__ __forceinline__ void sincos2pi(float u, float& s, float& c) {
#if __has_builtin(__builtin_amdgcn_fractf)
    float uf = __builtin_amdgcn_fractf(u);
#else
    float uf = u - floorf(u);
#endif
    asm("v_sin_f32 %0, %1" : "=v"(s) : "v"(uf));
    asm("v_cos_f32 %0, %1" : "=v"(c) : "v"(uf));
}

// 3x3 inverse (row-major), returns det.
__device__ __forceinline__ float inv3(const float* b, float* inv) {
    float c00 = b[4]*b[8] - b[5]*b[7];
    float c01 = b[2]*b[7] - b[1]*b[8];
    float c02 = b[1]*b[5] - b[2]*b[4];
    float c10 = b[5]*b[6] - b[3]*b[8];
    float c11 = b[0]*b[8] - b[2]*b[6];
    float c12 = b[2]*b[3] - b[0]*b[5];
    float c20 = b[3]*b[7] - b[4]*b[6];
    float c21 = b[1]*b[6] - b[0]*b[7];
    float c22 = b[0]*b[4] - b[1]*b[3];
    float det = b[0]*c00 + b[1]*c10 + b[2]*c20;
    float id = 1.0f/det;
    inv[0]=c00*id; inv[1]=c01*id; inv[2]=c02*id;
    inv[3]=c10*id; inv[4]=c11*id; inv[5]=c12*id;
    inv[6]=c20*id; inv[7]=c21*id; inv[8]=c22*id;
    return det;
}

// ---------------- fused prep:
// blocks [0,kb): k-vector prep -> pk1[k][16] = {ax,ay,az,g, axx,ayy,azz,axy, axz,ayz,..}
//                                 pk2[k][8]  = {ax,ay,az,(SrG),(SiG),..}
// blocks [kb,kb+nb): atom prep -> atom16[n][16] + per-block self-energy partials
__global__ __launch_bounds__(NT) void k_prep(
        const float* __restrict__ box, const float* __restrict__ kvecs,
        const float* __restrict__ coords, const float* __restrict__ q,
        const float* __restrict__ p, const float* __restrict__ t,
        float* __restrict__ pk1, float* __restrict__ pk2,
        float* __restrict__ atom16, float* __restrict__ selfp,
        int K, int N, int kb) {
    if ((int)blockIdx.x < kb) {
        int k = blockIdx.x*NT + threadIdx.x;
        if (k >= K) return;
        float bi[9]; float b[9];
        #pragma unroll
        for (int j=0;j<9;++j) b[j]=box[j];
        inv3(b, bi);
        float kx=kvecs[3*k], ky=kvecs[3*k+1], kz=kvecs[3*k+2];
        float ax = kx*bi[0] + ky*bi[3] + kz*bi[6];
        float ay = kx*bi[1] + ky*bi[4] + kz*bi[7];
        float az = kx*bi[2] + ky*bi[5] + kz*bi[8];
        float ksq = ax*ax + ay*ay + az*az;
        float g = expf(-PI_F*PI_F*ksq/(ALPHA_F*ALPHA_F)) / ksq;
        float* o = pk1 + 16*(size_t)k;
        o[0]=ax; o[1]=ay; o[2]=az; o[3]=g;
        o[4]=ax*ax; o[5]=ay*ay; o[6]=az*az; o[7]=ax*ay;
        o[8]=ax*az; o[9]=ay*az; o[10]=0.f; o[11]=0.f;
        o[12]=0.f; o[13]=0.f; o[14]=0.f; o[15]=0.f;
        float* o2 = pk2 + 8*(size_t)k;
        o2[0]=ax; o2[1]=ay; o2[2]=az; o2[3]=0.f; o2[4]=0.f; o2[5]=0.f; o2[6]=0.f; o2[7]=0.f;
    } else {
        int blk = blockIdx.x - kb;
        int n = blk*NT + threadIdx.x;
        float sq=0.f, sp=0.f, st=0.f;
        if (n < N) {
            const float c1 = TWO_PI_F*TWO_PI_F/3.0f;
            const float* tn = t + 9*(size_t)n;
            float* o = atom16 + 16*(size_t)n;
            o[0]=coords[3*n]; o[1]=coords[3*n+1]; o[2]=coords[3*n+2];
            float qq = q[n];
            o[3]=qq;
            float p0=p[3*n],p1=p[3*n+1],p2=p[3*n+2];
            o[4]=TWO_PI_F*p0; o[5]=TWO_PI_F*p1; o[6]=TWO_PI_F*p2;
            float t0=tn[0],t1=tn[1],t2=tn[2],t3=tn[3],t4=tn[4],
                  t5=tn[5],t6=tn[6],t7=tn[7],t8=tn[8];
            o[7]=c1*t0;
            o[8]=c1*t4; o[9]=c1*t8; o[10]=c1*(t1+t3); o[11]=c1*(t2+t6);
            o[12]=c1*(t5+t7); o[13]=0.f; o[14]=0.f; o[15]=0.f;
            sq = qq*qq;
            sp = p0*p0 + p1*p1 + p2*p2;
            st = t0*t0+t1*t1+t2*t2+t3*t3+t4*t4+t5*t5+t6*t6+t7*t7+t8*t8;
        }
        __shared__ float lds[3][4];
        int lane = threadIdx.x & 63, w = threadIdx.x >> 6;
        for (int o=32;o;o>>=1) {
            sq += __shfl_down(sq,o,64); sp += __shfl_down(sp,o,64); st += __shfl_down(st,o,64);
        }
        if (lane==0){ lds[0][w]=sq; lds[1][w]=sp; lds[2][w]=st; }
        __syncthreads();
        if (threadIdx.x==0){
            selfp[4*blk+0]=lds[0][0]+lds[0][1]+lds[0][2]+lds[0][3];
            selfp[4*blk+1]=lds[1][0]+lds[1][1]+lds[1][2]+lds[1][3];
            selfp[4*blk+2]=lds[2][0]+lds[2][1]+lds[2][2]+lds[2][3];
        }
    }
}

// ---------------- pass 1: lane = k, block stages ACHUNK atoms in LDS, loop with
// wave-uniform broadcast ds_read (no scalar-cache thrash), 2-deep reg pipeline.
__global__ __launch_bounds__(NT) void k_pass1(const float* __restrict__ pk1,
        const float* __restrict__ atom16, float* __restrict__ psr, float* __restrict__ psi,
        int N, int K) {
    __shared__ float4 lat[ACHUNK*4 + 4];
    int s = blockIdx.y;
    int n0 = s*ACHUNK;
    int m1 = min(ACHUNK, N - n0);
    // cooperative stage: m1 records (+1 pad record for prefetch), zero-filled tail
    const float4* ab = (const float4*)atom16;
    int base4 = n0*4;
    int total4 = N*4 + 4;       // atom16 has one pad record in ws
    for (int i = threadIdx.x; i < ACHUNK*4 + 4; i += NT) {
        float4 v = make_float4(0.f,0.f,0.f,0.f);
        if (base4 + i < total4) v = ab[base4 + i];
        lat[i] = v;
    }
    __syncthreads();

    int k = blockIdx.x*NT + threadIdx.x;
    float ax=0,ay=0,az=0,axx=0,ayy=0,azz=0,axy=0,axz=0,ayz=0;
    if (k < K) {
        const float* o = pk1 + 16*(size_t)k;
        ax=o[0]; ay=o[1]; az=o[2]; axx=o[4]; ayy=o[5]; azz=o[6];
        axy=o[7]; axz=o[8]; ayz=o[9];
    }
    float sr=0.f, si=0.f;
    float4 A0 = lat[0], A1 = lat[1], A2 = lat[2], A3 = lat[3];
    #pragma unroll 2
    for (int j = 0; j < m1; ++j) {
        float4 B0 = lat[4*(j+1)+0];
        float4 B1 = lat[4*(j+1)+1];
        float4 B2 = lat[4*(j+1)+2];
        float4 B3 = lat[4*(j+1)+3];
        float u = ax*A0.x + ay*A0.y + az*A0.z;
        float ss, cc; sincos2pi(u, ss, cc);
        float quad = axx*A1.w + ayy*A2.x + azz*A2.y + axy*A2.z + axz*A2.w + ayz*A3.x;
        float Lr = A0.w - quad;
        float Li = ax*A1.x + ay*A1.y + az*A1.z;
        sr += cc*Lr - ss*Li;
        si += cc*Li + ss*Lr;
        A0=B0; A1=B1; A2=B2; A3=B3;
    }
    if (k < K) { psr[(size_t)s*K + k] = sr; psi[(size_t)s*K + k] = si; }
}

// ---------------- reduce pass-1 partials -> SrG/SiG in pk2, per-block energy partials
__global__ __launch_bounds__(NT) void k_reduce1(const float* __restrict__ pk1,
                          const float* __restrict__ psr,
                          const float* __restrict__ psi, float* __restrict__ pk2,
                          float* __restrict__ eblk, int K, int nsplit) {
    int k = blockIdx.x*NT + threadIdx.x;
    float ek = 0.f;
    if (k < K) {
        float sr=0.f, si=0.f;
        #pragma unroll 4
        for (int s=0;s<nsplit;++s){ sr += psr[(size_t)s*K+k]; si += psi[(size_t)s*K+k]; }
        float g = pk1[16*(size_t)k + 3];
        float srg = g*sr, sig = g*si;
        pk2[8*(size_t)k+3] = srg;
        pk2[8*(size_t)k+4] = sig;
        ek = srg*sr + sig*si;
    }
    __shared__ float lds[4];
    int lane = threadIdx.x & 63, w = threadIdx.x >> 6;
    for (int o=32;o;o>>=1) ek += __shfl_down(ek,o,64);
    if (lane==0) lds[w]=ek;
    __syncthreads();
    if (threadIdx.x==0) eblk[blockIdx.x] = lds[0]+lds[1]+lds[2]+lds[3];
}

// ---------------- pass 2: lane = atom, block stages KCHUNK k-records in LDS.
__global__ __launch_bounds__(NT) void k_pass2(const float* __restrict__ coords,
        const float* __restrict__ pk2, float* __restrict__ part, int N, int K) {
    __shared__ float4 lkt[KCHUNK*2 + 2];
    int s = blockIdx.y;
    int ksplit = gridDim.y;
    int k0 = s*KCHUNK;
    int m1 = min(KCHUNK, K - k0);
    const float4* kb4 = (const float4*)pk2;
    int base4 = k0*2;
    int total4 = K*2 + 2;       // pk2 has one pad record in ws
    for (int i = threadIdx.x; i < KCHUNK*2 + 2; i += NT) {
        float4 v = make_float4(0.f,0.f,0.f,0.f);
        if (base4 + i < total4) v = kb4[base4 + i];
        lkt[i] = v;
    }
    __syncthreads();

    int n = blockIdx.x*NT + threadIdx.x;
    bool act = n < N;
    float rx=0.f,ry=0.f,rz=0.f;
    if (act){ rx=coords[3*n]; ry=coords[3*n+1]; rz=coords[3*n+2]; }
    float pot=0.f,fx=0.f,fy=0.f,fz=0.f;
    float4 A0 = lkt[0], A1 = lkt[1];
    #pragma unroll 2
    for (int j=0;j<m1;++j) {
        float4 B0 = lkt[2*(j+1)+0];
        float4 B1 = lkt[2*(j+1)+1];
        float u = A0.x*rx + A0.y*ry + A0.z*rz;
        float ss,cc; sincos2pi(u,ss,cc);
        float srg=A0.w, sig=A1.x;
        pot += srg*cc + sig*ss;
        float kim = srg*ss - sig*cc;
        fx += kim*A0.x; fy += kim*A0.y; fz += kim*A0.z;
        A0=B0; A1=B1;
    }
    if (act) {
        int SP = ksplit;
        part[(size_t)(0*SP+s)*N+n]=pot;
        part[(size_t)(1*SP+s)*N+n]=fx;
        part[(size_t)(2*SP+s)*N+n]=fy;
        part[(size_t)(3*SP+s)*N+n]=fz;
    }
}

// ---------------- finalize potential + field; block 0 finalizes energy
__global__ __launch_bounds__(NT) void k_fin(const float* __restrict__ part,
                      const float* __restrict__ q,
                      const float* __restrict__ p, const float* __restrict__ box,
                      const float* __restrict__ eblk, int nblk,
                      const float* __restrict__ selfp, int nself,
                      float* __restrict__ out, int N, int ksplit) {
    float b[9];
    #pragma unroll
    for (int j=0;j<9;++j) b[j]=box[j];
    float V = b[0]*(b[4]*b[8]-b[5]*b[7]) + b[1]*(b[5]*b[6]-b[3]*b[8]) + b[2]*(b[3]*b[7]-b[4]*b[6]);
    float arpi = ALPHA_F/sqrtf(PI_F);
    float a2 = ALPHA_F*ALPHA_F;
    if (blockIdx.x == 0) {
        int lane = threadIdx.x;
        if (lane >= 64) return;
        float e=0.f, sq=0.f, sp=0.f, st=0.f;
        for (int i=lane;i<nblk;i+=64) e += eblk[i];
        for (int i=lane;i<nself;i+=64){ sq+=selfp[4*i]; sp+=selfp[4*i+1]; st+=selfp[4*i+2]; }
        for (int o=32;o;o>>=1) {
            e += __shfl_down(e,o,64); sq += __shfl_down(sq,o,64);
            sp += __shfl_down(sp,o,64); st += __shfl_down(st,o,64);
        }
        if (lane==0) {
            out[0] = e/(PI_F*V) - arpi*sq - arpi*(2.0f*a2/3.0f)*sp
                   - arpi*(8.0f*a2*a2/45.0f)*st;
        }
        return;
    }
    int n = (blockIdx.x-1)*NT + threadIdx.x;
    if (n >= N) return;
    float sp=0.f,sfx=0.f,sfy=0.f,sfz=0.f;
    #pragma unroll 4
    for (int s=0;s<ksplit;++s){
        sp  += part[(size_t)(0*ksplit+s)*N+n];
        sfx += part[(size_t)(1*ksplit+s)*N+n];
        sfy += part[(size_t)(2*ksplit+s)*N+n];
        sfz += part[(size_t)(3*ksplit+s)*N+n];
    }
    out[1+n] = (2.0f/(PI_F*V))*sp - 2.0f*arpi*q[n];
    float cf = 4.0f/V;
    float cp2 = arpi*(4.0f*a2/3.0f);
    out[1+N+3*n+0] = cf*sfx + cp2*p[3*n+0];
    out[1+N+3*n+1] = cf*sfy + cp2*p[3*n+1];
    out[1+N+3*n+2] = cf*sfz + cp2*p[3*n+2];
}

extern "C" void kernel_launch(void* const* d_in, const int* in_sizes, int n_in,
                              void* d_out, int out_size, void* d_ws, size_t ws_size,
                              hipStream_t stream) {
    const float* coords = (const float*)d_in[0];
    const float* box    = (const float*)d_in[1];
    const float* q      = (const float*)d_in[2];
    const float* p      = (const float*)d_in[3];
    const float* t      = (const float*)d_in[4];
    const float* kvecs  = (const float*)d_in[5];
    int N = in_sizes[0]/3;
    int K = in_sizes[5]/3;
    float* ws = (float*)d_ws;

    int kb = (K + NT - 1)/NT;
    int nb = (N + NT - 1)/NT;
    int asplit = (N + ACHUNK - 1)/ACHUNK;   // 75 for N=6000
    int ksplit = (K + KCHUNK - 1)/KCHUNK;   // 93 for K=7812

    size_t off = 0;
    float* pk1    = ws + off; off += 16*(size_t)K;
    float* pk2    = ws + off; off += 8*(size_t)K + 8;      // +1 pad record
    float* atom16 = ws + off; off += 16*(size_t)N + 16;    // +1 pad record
    float* psr    = ws + off; off += (size_t)asplit*K;
    float* psi    = ws + off; off += (size_t)asplit*K;
    float* selfp  = ws + off; off += 4*(size_t)nb + 256;
    float* eblk   = ws + off; off += (size_t)kb + 64;
    float* part   = ws + off; off += 4*(size_t)ksplit*N;

    k_prep<<<kb + nb, NT, 0, stream>>>(box, kvecs, coords, q, p, t,
                                       pk1, pk2, atom16, selfp, K, N, kb);

    dim3 g1(kb, asplit);
    k_pass1<<<g1, NT, 0, stream>>>(pk1, atom16, psr, psi, N, K);
    k_reduce1<<<kb, NT, 0, stream>>>(pk1, psr, psi, pk2, eblk, K, asplit);

    dim3 g2(nb, ksplit);
    k_pass2<<<g2, NT, 0, stream>>>(coords, pk2, part, N, K);
    k_fin  <<<nb + 1, NT, 0, stream>>>(part, q, p, box, eblk, kb, selfp, nb,
                                       (float*)d_out, N, ksplit);
}

// Round 5
// 116.316 us; speedup vs baseline: 1.4264x; 1.0043x over previous
//
#include <hip/hip_runtime.h>

#define PI_F      3.14159265358979f
#define TWO_PI_F  6.28318530717959f
#define ALPHA_F   0.3f
#define NT        256
#define NT1       128   // pass-1 block size
#define NT2       128   // pass-2 block size
#define M1        4     // k-vectors per thread in pass 1
#define M2        4     // atoms per thread in pass 2
#define ACHUNK    40    // atoms staged per pass-1 chunk
#define KCHUNK    56    // k-records staged per pass-2 chunk

// sin/cos of 2*pi*u using the hardware trig units (input in revolutions).
__device__ __forceinline__ void sincos2pi(float u, float& s, float& c) {
#if __has_builtin(__builtin_amdgcn_fractf)
    float uf = __builtin_amdgcn_fractf(u);
#else
    float uf = u - floorf(u);
#endif
    asm("v_sin_f32 %0, %1" : "=v"(s) : "v"(uf));
    asm("v_cos_f32 %0, %1" : "=v"(c) : "v"(uf));
}

// 3x3 inverse (row-major), returns det.
__device__ __forceinline__ float inv3(const float* b, float* inv) {
    float c00 = b[4]*b[8] - b[5]*b[7];
    float c01 = b[2]*b[7] - b[1]*b[8];
    float c02 = b[1]*b[5] - b[2]*b[4];
    float c10 = b[5]*b[6] - b[3]*b[8];
    float c11 = b[0]*b[8] - b[2]*b[6];
    float c12 = b[2]*b[3] - b[0]*b[5];
    float c20 = b[3]*b[7] - b[4]*b[6];
    float c21 = b[1]*b[6] - b[0]*b[7];
    float c22 = b[0]*b[4] - b[1]*b[3];
    float det = b[0]*c00 + b[1]*c10 + b[2]*c20;
    float id = 1.0f/det;
    inv[0]=c00*id; inv[1]=c01*id; inv[2]=c02*id;
    inv[3]=c10*id; inv[4]=c11*id; inv[5]=c12*id;
    inv[6]=c20*id; inv[7]=c21*id; inv[8]=c22*id;
    return det;
}

// ---------------- fused prep (unchanged structure)
__global__ __launch_bounds__(NT) void k_prep(
        const float* __restrict__ box, const float* __restrict__ kvecs,
        const float* __restrict__ coords, const float* __restrict__ q,
        const float* __restrict__ p, const float* __restrict__ t,
        float* __restrict__ pk1, float* __restrict__ pk2,
        float* __restrict__ atom16, float* __restrict__ selfp,
        int K, int N, int kb) {
    if ((int)blockIdx.x < kb) {
        int k = blockIdx.x*NT + threadIdx.x;
        if (k >= K) return;
        float bi[9]; float b[9];
        #pragma unroll
        for (int j=0;j<9;++j) b[j]=box[j];
        inv3(b, bi);
        float kx=kvecs[3*k], ky=kvecs[3*k+1], kz=kvecs[3*k+2];
        float ax = kx*bi[0] + ky*bi[3] + kz*bi[6];
        float ay = kx*bi[1] + ky*bi[4] + kz*bi[7];
        float az = kx*bi[2] + ky*bi[5] + kz*bi[8];
        float ksq = ax*ax + ay*ay + az*az;
        float g = expf(-PI_F*PI_F*ksq/(ALPHA_F*ALPHA_F)) / ksq;
        float* o = pk1 + 16*(size_t)k;
        o[0]=ax; o[1]=ay; o[2]=az; o[3]=g;
        o[4]=ax*ax; o[5]=ay*ay; o[6]=az*az; o[7]=ax*ay;
        o[8]=ax*az; o[9]=ay*az; o[10]=0.f; o[11]=0.f;
        o[12]=0.f; o[13]=0.f; o[14]=0.f; o[15]=0.f;
        float* o2 = pk2 + 8*(size_t)k;
        o2[0]=ax; o2[1]=ay; o2[2]=az; o2[3]=0.f; o2[4]=0.f; o2[5]=0.f; o2[6]=0.f; o2[7]=0.f;
    } else {
        int blk = blockIdx.x - kb;
        int n = blk*NT + threadIdx.x;
        float sq=0.f, sp=0.f, st=0.f;
        if (n < N) {
            const float c1 = TWO_PI_F*TWO_PI_F/3.0f;
            const float* tn = t + 9*(size_t)n;
            float* o = atom16 + 16*(size_t)n;
            o[0]=coords[3*n]; o[1]=coords[3*n+1]; o[2]=coords[3*n+2];
            float qq = q[n];
            o[3]=qq;
            float p0=p[3*n],p1=p[3*n+1],p2=p[3*n+2];
            o[4]=TWO_PI_F*p0; o[5]=TWO_PI_F*p1; o[6]=TWO_PI_F*p2;
            float t0=tn[0],t1=tn[1],t2=tn[2],t3=tn[3],t4=tn[4],
                  t5=tn[5],t6=tn[6],t7=tn[7],t8=tn[8];
            o[7]=c1*t0;
            o[8]=c1*t4; o[9]=c1*t8; o[10]=c1*(t1+t3); o[11]=c1*(t2+t6);
            o[12]=c1*(t5+t7); o[13]=0.f; o[14]=0.f; o[15]=0.f;
            sq = qq*qq;
            sp = p0*p0 + p1*p1 + p2*p2;
            st = t0*t0+t1*t1+t2*t2+t3*t3+t4*t4+t5*t5+t6*t6+t7*t7+t8*t8;
        }
        __shared__ float lds[3][4];
        int lane = threadIdx.x & 63, w = threadIdx.x >> 6;
        for (int o=32;o;o>>=1) {
            sq += __shfl_down(sq,o,64); sp += __shfl_down(sp,o,64); st += __shfl_down(st,o,64);
        }
        if (lane==0){ lds[0][w]=sq; lds[1][w]=sp; lds[2][w]=st; }
        __syncthreads();
        if (threadIdx.x==0){
            selfp[4*blk+0]=lds[0][0]+lds[0][1]+lds[0][2]+lds[0][3];
            selfp[4*blk+1]=lds[1][0]+lds[1][1]+lds[1][2]+lds[1][3];
            selfp[4*blk+2]=lds[2][0]+lds[2][1]+lds[2][2]+lds[2][3];
        }
    }
}

// ---------------- pass 1: each thread owns M1 k-vectors (stride gridDim.x*NT1);
// block stages ACHUNK atoms in LDS; broadcast ds_read amortized over M1 k's.
// blockIdx.y = s0 handles chunks s0, s0+S1, ... accumulating in registers.
__global__ __launch_bounds__(NT1) void k_pass1(const float* __restrict__ pk1,
        const float* __restrict__ atom16, float* __restrict__ psr, float* __restrict__ psi,
        int N, int K) {
    __shared__ float4 lat[(ACHUNK+1)*4];
    int S1 = gridDim.y, s0 = blockIdx.y;
    int KSTEP = gridDim.x*NT1;
    int kbase = blockIdx.x*NT1 + threadIdx.x;
    float ax[M1],ay[M1],az[M1],axx[M1],ayy[M1],azz[M1],axy[M1],axz[M1],ayz[M1];
    #pragma unroll
    for (int m=0;m<M1;++m){
        int k = kbase + m*KSTEP;
        if (k < K) {
            const float* o = pk1 + 16*(size_t)k;
            ax[m]=o[0];ay[m]=o[1];az[m]=o[2];axx[m]=o[4];ayy[m]=o[5];azz[m]=o[6];
            axy[m]=o[7];axz[m]=o[8];ayz[m]=o[9];
        } else {
            ax[m]=0.f;ay[m]=0.f;az[m]=0.f;axx[m]=0.f;ayy[m]=0.f;azz[m]=0.f;
            axy[m]=0.f;axz[m]=0.f;ayz[m]=0.f;
        }
    }
    float sr[M1], si[M1];
    #pragma unroll
    for (int m=0;m<M1;++m){ sr[m]=0.f; si[m]=0.f; }
    const float4* ab = (const float4*)atom16;
    int total4 = N*4 + 4;      // atom16 has one pad record
    bool first = true;
    for (int c = s0; c*ACHUNK < N; c += S1) {
        int n0 = c*ACHUNK;
        int mcnt = min(ACHUNK, N - n0);
        if (!first) __syncthreads();
        first = false;
        int base4 = n0*4;
        for (int i = threadIdx.x; i < (ACHUNK+1)*4; i += NT1) {
            float4 v = make_float4(0.f,0.f,0.f,0.f);
            if (base4 + i < total4) v = ab[base4+i];
            lat[i] = v;
        }
        __syncthreads();
        float4 A0=lat[0],A1=lat[1],A2=lat[2],A3=lat[3];
        #pragma unroll 2
        for (int j=0;j<mcnt;++j) {
            float4 B0=lat[4*(j+1)+0], B1=lat[4*(j+1)+1];
            float4 B2=lat[4*(j+1)+2], B3=lat[4*(j+1)+3];
            #pragma unroll
            for (int m=0;m<M1;++m) {
                float u = ax[m]*A0.x + ay[m]*A0.y + az[m]*A0.z;
                float ss,cc; sincos2pi(u,ss,cc);
                float quad = axx[m]*A1.w + ayy[m]*A2.x + azz[m]*A2.y
                           + axy[m]*A2.z + axz[m]*A2.w + ayz[m]*A3.x;
                float Lr = A0.w - quad;
                float Li = ax[m]*A1.x + ay[m]*A1.y + az[m]*A1.z;
                sr[m] = fmaf(cc,Lr,sr[m]); sr[m] = fmaf(-ss,Li,sr[m]);
                si[m] = fmaf(cc,Li,si[m]); si[m] = fmaf(ss,Lr,si[m]);
            }
            A0=B0;A1=B1;A2=B2;A3=B3;
        }
    }
    #pragma unroll
    for (int m=0;m<M1;++m) {
        int k = kbase + m*KSTEP;
        if (k < K) { psr[(size_t)s0*K+k]=sr[m]; psi[(size_t)s0*K+k]=si[m]; }
    }
}

// ---------------- reduce pass-1 partials -> SrG/SiG in pk2, per-block energy partials
__global__ __launch_bounds__(NT) void k_reduce1(const float* __restrict__ pk1,
                          const float* __restrict__ psr,
                          const float* __restrict__ psi, float* __restrict__ pk2,
                          float* __restrict__ eblk, int K, int nsplit) {
    int k = blockIdx.x*NT + threadIdx.x;
    float ek = 0.f;
    if (k < K) {
        float sr=0.f, si=0.f;
        #pragma unroll 4
        for (int s=0;s<nsplit;++s){ sr += psr[(size_t)s*K+k]; si += psi[(size_t)s*K+k]; }
        float g = pk1[16*(size_t)k + 3];
        float srg = g*sr, sig = g*si;
        pk2[8*(size_t)k+3] = srg;
        pk2[8*(size_t)k+4] = sig;
        ek = srg*sr + sig*si;
    }
    __shared__ float lds[4];
    int lane = threadIdx.x & 63, w = threadIdx.x >> 6;
    for (int o=32;o;o>>=1) ek += __shfl_down(ek,o,64);
    if (lane==0) lds[w]=ek;
    __syncthreads();
    if (threadIdx.x==0) eblk[blockIdx.x] = lds[0]+lds[1]+lds[2]+lds[3];
}

// ---------------- pass 2: each thread owns M2 atoms; block stages KCHUNK k-records.
__global__ __launch_bounds__(NT2) void k_pass2(const float* __restrict__ coords,
        const float* __restrict__ pk2, float* __restrict__ part, int N, int K) {
    __shared__ float4 lkt[(KCHUNK+1)*2];
    int S2 = gridDim.y, s0 = blockIdx.y;
    int NSTEP = gridDim.x*NT2;
    int nbase = blockIdx.x*NT2 + threadIdx.x;
    float rx[M2],ry[M2],rz[M2],pot[M2],fx[M2],fy[M2],fz[M2];
    #pragma unroll
    for (int m=0;m<M2;++m){
        int n = nbase + m*NSTEP;
        if (n < N){ rx[m]=coords[3*n]; ry[m]=coords[3*n+1]; rz[m]=coords[3*n+2]; }
        else { rx[m]=0.f; ry[m]=0.f; rz[m]=0.f; }
        pot[m]=0.f; fx[m]=0.f; fy[m]=0.f; fz[m]=0.f;
    }
    const float4* kb4 = (const float4*)pk2;
    int total4 = K*2 + 2;      // pk2 has one pad record
    bool first = true;
    for (int c = s0; c*KCHUNK < K; c += S2) {
        int k0 = c*KCHUNK;
        int mcnt = min(KCHUNK, K - k0);
        if (!first) __syncthreads();
        first = false;
        int base4 = k0*2;
        for (int i = threadIdx.x; i < (KCHUNK+1)*2; i += NT2) {
            float4 v = make_float4(0.f,0.f,0.f,0.f);
            if (base4 + i < total4) v = kb4[base4+i];
            lkt[i] = v;
        }
        __syncthreads();
        float4 A0=lkt[0], A1=lkt[1];
        #pragma unroll 2
        for (int j=0;j<mcnt;++j) {
            float4 B0=lkt[2*(j+1)+0], B1=lkt[2*(j+1)+1];
            #pragma unroll
            for (int m=0;m<M2;++m) {
                float u = A0.x*rx[m] + A0.y*ry[m] + A0.z*rz[m];
                float ss,cc; sincos2pi(u,ss,cc);
                pot[m] = fmaf(A0.w,cc,pot[m]); pot[m] = fmaf(A1.x,ss,pot[m]);
                float kim = A0.w*ss - A1.x*cc;
                fx[m] = fmaf(kim,A0.x,fx[m]);
                fy[m] = fmaf(kim,A0.y,fy[m]);
                fz[m] = fmaf(kim,A0.z,fz[m]);
            }
            A0=B0; A1=B1;
        }
    }
    #pragma unroll
    for (int m=0;m<M2;++m) {
        int n = nbase + m*NSTEP;
        if (n < N) {
            part[(size_t)(0*S2+s0)*N+n]=pot[m];
            part[(size_t)(1*S2+s0)*N+n]=fx[m];
            part[(size_t)(2*S2+s0)*N+n]=fy[m];
            part[(size_t)(3*S2+s0)*N+n]=fz[m];
        }
    }
}

// ---------------- finalize potential + field; block 0 finalizes energy
__global__ __launch_bounds__(NT) void k_fin(const float* __restrict__ part,
                      const float* __restrict__ q,
                      const float* __restrict__ p, const float* __restrict__ box,
                      const float* __restrict__ eblk, int nblk,
                      const float* __restrict__ selfp, int nself,
                      float* __restrict__ out, int N, int ksplit) {
    float b[9];
    #pragma unroll
    for (int j=0;j<9;++j) b[j]=box[j];
    float V = b[0]*(b[4]*b[8]-b[5]*b[7]) + b[1]*(b[5]*b[6]-b[3]*b[8]) + b[2]*(b[3]*b[7]-b[4]*b[6]);
    float arpi = ALPHA_F/sqrtf(PI_F);
    float a2 = ALPHA_F*ALPHA_F;
    if (blockIdx.x == 0) {
        int lane = threadIdx.x;
        if (lane >= 64) return;
        float e=0.f, sq=0.f, sp=0.f, st=0.f;
        for (int i=lane;i<nblk;i+=64) e += eblk[i];
        for (int i=lane;i<nself;i+=64){ sq+=selfp[4*i]; sp+=selfp[4*i+1]; st+=selfp[4*i+2]; }
        for (int o=32;o;o>>=1) {
            e += __shfl_down(e,o,64); sq += __shfl_down(sq,o,64);
            sp += __shfl_down(sp,o,64); st += __shfl_down(st,o,64);
        }
        if (lane==0) {
            out[0] = e/(PI_F*V) - arpi*sq - arpi*(2.0f*a2/3.0f)*sp
                   - arpi*(8.0f*a2*a2/45.0f)*st;
        }
        return;
    }
    int n = (blockIdx.x-1)*NT + threadIdx.x;
    if (n >= N) return;
    float sp=0.f,sfx=0.f,sfy=0.f,sfz=0.f;
    #pragma unroll 4
    for (int s=0;s<ksplit;++s){
        sp  += part[(size_t)(0*ksplit+s)*N+n];
        sfx += part[(size_t)(1*ksplit+s)*N+n];
        sfy += part[(size_t)(2*ksplit+s)*N+n];
        sfz += part[(size_t)(3*ksplit+s)*N+n];
    }
    out[1+n] = (2.0f/(PI_F*V))*sp - 2.0f*arpi*q[n];
    float cf = 4.0f/V;
    float cp2 = arpi*(4.0f*a2/3.0f);
    out[1+N+3*n+0] = cf*sfx + cp2*p[3*n+0];
    out[1+N+3*n+1] = cf*sfy + cp2*p[3*n+1];
    out[1+N+3*n+2] = cf*sfz + cp2*p[3*n+2];
}

extern "C" void kernel_launch(void* const* d_in, const int* in_sizes, int n_in,
                              void* d_out, int out_size, void* d_ws, size_t ws_size,
                              hipStream_t stream) {
    const float* coords = (const float*)d_in[0];
    const float* box    = (const float*)d_in[1];
    const float* q      = (const float*)d_in[2];
    const float* p      = (const float*)d_in[3];
    const float* t      = (const float*)d_in[4];
    const float* kvecs  = (const float*)d_in[5];
    int N = in_sizes[0]/3;
    int K = in_sizes[5]/3;
    float* ws = (float*)d_ws;
    size_t ws_floats = ws_size / 4;

    int kb = (K + NT - 1)/NT;
    int nb = (N + NT - 1)/NT;
    int chunks1 = (N + ACHUNK - 1)/ACHUNK;   // 150
    int chunks2 = (K + KCHUNK - 1)/KCHUNK;   // 140
    int S1 = chunks1, S2 = chunks2;

    auto need = [&](int s1, int s2)->size_t {
        return 16*(size_t)K + 8*(size_t)K + 8 + 16*(size_t)N + 16
             + 2*(size_t)s1*K + 4*(size_t)nb + 256 + (size_t)kb + 64
             + 4*(size_t)s2*N;
    };
    // shrink whichever partial array is larger until it fits
    while (need(S1,S2) > ws_floats && (S1 > 2 || S2 > 2)) {
        size_t b1 = 2*(size_t)S1*K, b2 = 4*(size_t)S2*N;
        if (b2 >= b1 && S2 > 2) S2 = (S2+1)/2;
        else S1 = (S1+1)/2;
    }

    size_t off = 0;
    float* pk1    = ws + off; off += 16*(size_t)K;
    float* pk2    = ws + off; off += 8*(size_t)K + 8;      // +1 pad record
    float* atom16 = ws + off; off += 16*(size_t)N + 16;    // +1 pad record
    float* psr    = ws + off; off += (size_t)S1*K;
    float* psi    = ws + off; off += (size_t)S1*K;
    float* selfp  = ws + off; off += 4*(size_t)nb + 256;
    float* eblk   = ws + off; off += (size_t)kb + 64;
    float* part   = ws + off; off += 4*(size_t)S2*N;

    k_prep<<<kb + nb, NT, 0, stream>>>(box, kvecs, coords, q, p, t,
                                       pk1, pk2, atom16, selfp, K, N, kb);

    int gx1 = (K + NT1*M1 - 1)/(NT1*M1);     // 16
    dim3 g1(gx1, S1);
    k_pass1<<<g1, NT1, 0, stream>>>(pk1, atom16, psr, psi, N, K);
    k_reduce1<<<kb, NT, 0, stream>>>(pk1, psr, psi, pk2, eblk, K, S1);

    int gx2 = (N + NT2*M2 - 1)/(NT2*M2);     // 12
    dim3 g2(gx2, S2);
    k_pass2<<<g2, NT2, 0, stream>>>(coords, pk2, part, N, K);
    k_fin  <<<nb + 1, NT, 0, stream>>>(part, q, p, box, eblk, kb, selfp, nb,
                                       (float*)d_out, N, S2);
}

// Round 6
// 81.242 us; speedup vs baseline: 2.0422x; 1.4317x over previous
//
#include <hip/hip_runtime.h>

#define PI_F      3.14159265358979f
#define TWO_PI_F  6.28318530717959f
#define ALPHA_F   0.3f
#define NT        256
#define NT1       128
#define NT2       128
#define L1        5     // kz slots per pass-1 thread segment
#define M2        4     // atoms per pass-2 thread
#define ACHUNK    40    // atoms staged per pass-1 chunk
#define LL        2     // k-lines per pass-2 split
#define RS        8     // reduce1 sub-splits

// sin/cos of 2*pi*u using the hardware trig units (input in revolutions).
__device__ __forceinline__ void sincos2pi(float u, float& s, float& c) {
#if __has_builtin(__builtin_amdgcn_fractf)
    float uf = __builtin_amdgcn_fractf(u);
#else
    float uf = u - floorf(u);
#endif
    asm("v_sin_f32 %0, %1" : "=v"(s) : "v"(uf));
    asm("v_cos_f32 %0, %1" : "=v"(c) : "v"(uf));
}

// 3x3 inverse (row-major), returns det.
__device__ __forceinline__ float inv3(const float* b, float* inv) {
    float c00 = b[4]*b[8] - b[5]*b[7];
    float c01 = b[2]*b[7] - b[1]*b[8];
    float c02 = b[1]*b[5] - b[2]*b[4];
    float c10 = b[5]*b[6] - b[3]*b[8];
    float c11 = b[0]*b[8] - b[2]*b[6];
    float c12 = b[2]*b[3] - b[0]*b[5];
    float c20 = b[3]*b[7] - b[4]*b[6];
    float c21 = b[1]*b[6] - b[0]*b[7];
    float c22 = b[0]*b[4] - b[1]*b[3];
    float det = b[0]*c00 + b[1]*c10 + b[2]*c20;
    float id = 1.0f/det;
    inv[0]=c00*id; inv[1]=c01*id; inv[2]=c02*id;
    inv[3]=c10*id; inv[4]=c11*id; inv[5]=c12*id;
    inv[6]=c20*id; inv[7]=c21*id; inv[8]=c22*id;
    return det;
}

// map original k index -> (line, slot). kz = slot - kmax, uniform for ALL lines.
__device__ __forceinline__ void kmap(int k, int kmax, int LINELEN, int& line, int& slot) {
    if (k < kmax) { line = 0; slot = k + 1 + kmax; }
    else { int r = k - kmax; line = 1 + r / LINELEN; slot = r % LINELEN; }
}

// ---------------- fused prep:
// blocks [0,kb): per-k gaussian -> gk[k]; block 0 zeroes pk2p pads (line 0, slots 0..kmax)
// blocks [kb,kb+nb): atom records (lattice basis) + self-energy partials
//   atom16[n][16] = {u1,u2,u3,q, c3,s3,P1,P2, P3,M11,M22,M33, M12p,M13p,M23p,0}
__global__ __launch_bounds__(NT) void k_prep(
        const float* __restrict__ box, const float* __restrict__ kvecs,
        const float* __restrict__ coords, const float* __restrict__ q,
        const float* __restrict__ p, const float* __restrict__ t,
        float* __restrict__ gk, float* __restrict__ pk2p,
        float* __restrict__ atom16, float* __restrict__ selfp,
        int K, int N, int kb, int kmax) {
    float b[9], bi[9];
    #pragma unroll
    for (int j=0;j<9;++j) b[j]=box[j];
    inv3(b, bi);
    if ((int)blockIdx.x < kb) {
        if (blockIdx.x == 0 && (int)threadIdx.x < 2*(kmax+1))
            pk2p[threadIdx.x] = 0.f;
        int k = blockIdx.x*NT + threadIdx.x;
        if (k >= K) return;
        float kx=kvecs[3*k], ky=kvecs[3*k+1], kz=kvecs[3*k+2];
        float ax = kx*bi[0] + ky*bi[3] + kz*bi[6];
        float ay = kx*bi[1] + ky*bi[4] + kz*bi[7];
        float az = kx*bi[2] + ky*bi[5] + kz*bi[8];
        float ksq = ax*ax + ay*ay + az*az;
        gk[k] = expf(-PI_F*PI_F*ksq/(ALPHA_F*ALPHA_F)) / ksq;
    } else {
        int blk = blockIdx.x - kb;
        int n = blk*NT + threadIdx.x;
        float sq=0.f, sp=0.f, st=0.f;
        if (n < N) {
            const float c1 = TWO_PI_F*TWO_PI_F/3.0f;
            const float* tn = t + 9*(size_t)n;
            float rx=coords[3*n], ry=coords[3*n+1], rz=coords[3*n+2];
            float qq = q[n];
            float p0=p[3*n],p1=p[3*n+1],p2=p[3*n+2];
            float u1 = bi[0]*rx + bi[1]*ry + bi[2]*rz;
            float u2 = bi[3]*rx + bi[4]*ry + bi[5]*rz;
            float u3 = bi[6]*rx + bi[7]*ry + bi[8]*rz;
            float P1 = TWO_PI_F*(bi[0]*p0 + bi[1]*p1 + bi[2]*p2);
            float P2 = TWO_PI_F*(bi[3]*p0 + bi[4]*p1 + bi[5]*p2);
            float P3 = TWO_PI_F*(bi[6]*p0 + bi[7]*p1 + bi[8]*p2);
            float t0=tn[0],t1=tn[1],t2=tn[2],t3=tn[3],t4=tn[4],
                  t5=tn[5],t6=tn[6],t7=tn[7],t8=tn[8];
            // w_a[j] = sum_i Ba[i] t[i][j]  (Ba = row a of box_inv)
            float w1x = bi[0]*t0 + bi[1]*t3 + bi[2]*t6;
            float w1y = bi[0]*t1 + bi[1]*t4 + bi[2]*t7;
            float w1z = bi[0]*t2 + bi[1]*t5 + bi[2]*t8;
            float w2x = bi[3]*t0 + bi[4]*t3 + bi[5]*t6;
            float w2y = bi[3]*t1 + bi[4]*t4 + bi[5]*t7;
            float w2z = bi[3]*t2 + bi[4]*t5 + bi[5]*t8;
            float w3x = bi[6]*t0 + bi[7]*t3 + bi[8]*t6;
            float w3y = bi[6]*t1 + bi[7]*t4 + bi[8]*t7;
            float w3z = bi[6]*t2 + bi[7]*t5 + bi[8]*t8;
            float Q11 = w1x*bi[0] + w1y*bi[1] + w1z*bi[2];
            float Q12 = w1x*bi[3] + w1y*bi[4] + w1z*bi[5];
            float Q13 = w1x*bi[6] + w1y*bi[7] + w1z*bi[8];
            float Q21 = w2x*bi[0] + w2y*bi[1] + w2z*bi[2];
            float Q22 = w2x*bi[3] + w2y*bi[4] + w2z*bi[5];
            float Q23 = w2x*bi[6] + w2y*bi[7] + w2z*bi[8];
            float Q31 = w3x*bi[0] + w3y*bi[1] + w3z*bi[2];
            float Q32 = w3x*bi[3] + w3y*bi[4] + w3z*bi[5];
            float Q33 = w3x*bi[6] + w3y*bi[7] + w3z*bi[8];
            float c3v, s3v; sincos2pi(u3, s3v, c3v);
            float* o = atom16 + 16*(size_t)n;
            o[0]=u1; o[1]=u2; o[2]=u3; o[3]=qq;
            o[4]=c3v; o[5]=s3v; o[6]=P1; o[7]=P2;
            o[8]=P3; o[9]=c1*Q11; o[10]=c1*Q22; o[11]=c1*Q33;
            o[12]=c1*(Q12+Q21); o[13]=c1*(Q13+Q31); o[14]=c1*(Q23+Q32); o[15]=0.f;
            sq = qq*qq;
            sp = p0*p0 + p1*p1 + p2*p2;
            st = t0*t0+t1*t1+t2*t2+t3*t3+t4*t4+t5*t5+t6*t6+t7*t7+t8*t8;
        }
        __shared__ float lds[3][4];
        int lane = threadIdx.x & 63, w = threadIdx.x >> 6;
        for (int o=32;o;o>>=1) {
            sq += __shfl_down(sq,o,64); sp += __shfl_down(sp,o,64); st += __shfl_down(st,o,64);
        }
        if (lane==0){ lds[0][w]=sq; lds[1][w]=sp; lds[2][w]=st; }
        __syncthreads();
        if (threadIdx.x==0){
            selfp[4*blk+0]=lds[0][0]+lds[0][1]+lds[0][2]+lds[0][3];
            selfp[4*blk+1]=lds[1][0]+lds[1][1]+lds[1][2]+lds[1][3];
            selfp[4*blk+2]=lds[2][0]+lds[2][1]+lds[2][2]+lds[2][3];
        }
    }
}

// ---------------- pass 1: thread owns a kz-segment of L1 slots on one (kx,ky) line.
// Per atom: 1 sincos + complex-rotation recurrence along kz. Atoms staged in LDS.
__global__ __launch_bounds__(NT1) void k_pass1(
        const float* __restrict__ atom16, float* __restrict__ psr, float* __restrict__ psi,
        int N, int kmax, int NL, int SEGPL, int LPAD, int K2) {
    __shared__ float4 lat[(ACHUNK+1)*4];
    int LINELEN = 2*kmax+1;
    int S1 = gridDim.y, s0 = blockIdx.y;
    int seg = blockIdx.x*NT1 + threadIdx.x;
    int line = seg / SEGPL;
    int sidx = seg - line*SEGPL;
    bool act = line < NL;
    int kxi=0, kyi=0;
    if (act) {
        if (line == 0) { kxi=0; kyi=0; }
        else if (line <= kmax) { kxi=0; kyi=line; }
        else { int lp = line - kmax - 1; kxi = 1 + lp/LINELEN; kyi = lp - (kxi-1)*LINELEN - kmax; }
    }
    float fkx = (float)kxi, fky = (float)kyi;
    float fkz0 = act ? (float)(sidx*L1 - kmax) : 0.f;
    float kx2 = fkx*fkx, kxky = fkx*fky, ky2 = fky*fky;
    float kz02 = fkz0*fkz0, tkz0 = 2.0f*fkz0;

    float sr[L1], si[L1];
    #pragma unroll
    for (int j=0;j<L1;++j){ sr[j]=0.f; si[j]=0.f; }

    const float4* ab = (const float4*)atom16;
    int total4 = N*4 + 4;
    bool first = true;
    for (int c = s0; c*ACHUNK < N; c += S1) {
        int n0 = c*ACHUNK;
        int mcnt = min(ACHUNK, N - n0);
        if (!first) __syncthreads();
        first = false;
        int base4 = n0*4;
        for (int i = threadIdx.x; i < (ACHUNK+1)*4; i += NT1) {
            float4 v = make_float4(0.f,0.f,0.f,0.f);
            if (base4 + i < total4) v = ab[base4+i];
            lat[i] = v;
        }
        __syncthreads();
        float4 A0=lat[0],A1=lat[1],A2=lat[2],A3=lat[3];
        #pragma unroll 2
        for (int j=0;j<mcnt;++j) {
            float4 B0=lat[4*(j+1)+0], B1=lat[4*(j+1)+1];
            float4 B2=lat[4*(j+1)+2], B3=lat[4*(j+1)+3];
            float u1=A0.x, u2=A0.y, u3=A0.z, qn=A0.w;
            float c3=A1.x, s3=A1.y, P1=A1.z, P2=A1.w;
            float P3=A2.x, M11=A2.y, M22=A2.z, M33=A2.w;
            float M12=A3.x, M13=A3.y, M23=A3.z;
            float ub = fkx*u1 + fky*u2 + fkz0*u3;
            float cc, ss; sincos2pi(ub, ss, cc);
            float Lib = fkx*P1 + fky*P2 + fkz0*P3;
            float Aq = kx2*M11 + kxky*M12 + ky2*M22;
            float Bq = fkx*M13 + fky*M23;
            float Cq = M33;
            float A2q = Aq + fkz0*Bq + kz02*Cq;
            float B2q = fmaf(tkz0, Cq, Bq);
            #pragma unroll
            for (int jj=0;jj<L1;++jj) {
                float jf = (float)jj;
                float quad = fmaf(jf*jf, Cq, fmaf(jf, B2q, A2q));
                float Li = fmaf(jf, P3, Lib);
                float Lr = qn - quad;
                sr[jj] = fmaf(cc, Lr, sr[jj]); sr[jj] = fmaf(-ss, Li, sr[jj]);
                si[jj] = fmaf(cc, Li, si[jj]); si[jj] = fmaf(ss, Lr, si[jj]);
                if (jj+1 < L1) {
                    float tmp = ss*s3;
                    float cn = fmaf(cc, c3, -tmp);
                    float tmp2 = cc*s3;
                    float sn = fmaf(ss, c3, tmp2);
                    cc = cn; ss = sn;
                }
            }
            A0=B0;A1=B1;A2=B2;A3=B3;
        }
    }
    if (act) {
        size_t base = (size_t)s0*K2 + (size_t)line*LPAD + sidx*L1;
        #pragma unroll
        for (int j=0;j<L1;++j){ psr[base+j]=sr[j]; psi[base+j]=si[j]; }
    }
}

// ---------------- reduce1: sub-reduce S1 partials (strided by RS) per original k
__global__ __launch_bounds__(NT) void k_reduce1(const float* __restrict__ psr,
        const float* __restrict__ psi, float* __restrict__ pred,
        int K, int K2, int S1, int kmax, int LPAD) {
    int k = blockIdx.x*NT + threadIdx.x;
    if (k >= K) return;
    int LINELEN = 2*kmax+1;
    int line, slot; kmap(k, kmax, LINELEN, line, slot);
    size_t pk = (size_t)line*LPAD + slot;
    int rs = blockIdx.y;
    float sr=0.f, si=0.f;
    for (int s = rs; s < S1; s += RS) {
        sr += psr[(size_t)s*K2 + pk];
        si += psi[(size_t)s*K2 + pk];
    }
    pred[((size_t)rs*K + k)*2 + 0] = sr;
    pred[((size_t)rs*K + k)*2 + 1] = si;
}

// ---------------- reduce2: finish reduction, write SrG/SiG into padded line layout + energy partials
__global__ __launch_bounds__(NT) void k_reduce2(const float* __restrict__ pred,
        const float* __restrict__ gk, float* __restrict__ pk2p,
        float* __restrict__ eblk, int K, int kmax) {
    int k = blockIdx.x*NT + threadIdx.x;
    float ek = 0.f;
    if (k < K) {
        float sr=0.f, si=0.f;
        #pragma unroll
        for (int rs=0; rs<RS; ++rs) {
            sr += pred[((size_t)rs*K + k)*2 + 0];
            si += pred[((size_t)rs*K + k)*2 + 1];
        }
        int LINELEN = 2*kmax+1;
        int line, slot; kmap(k, kmax, LINELEN, line, slot);
        float g = gk[k];
        float srg = g*sr, sig = g*si;
        pk2p[((size_t)line*LINELEN + slot)*2 + 0] = srg;
        pk2p[((size_t)line*LINELEN + slot)*2 + 1] = sig;
        ek = srg*sr + sig*si;
    }
    __shared__ float lds[4];
    int lane = threadIdx.x & 63, w = threadIdx.x >> 6;
    for (int o=32;o;o>>=1) ek += __shfl_down(ek,o,64);
    if (lane==0) lds[w]=ek;
    __syncthreads();
    if (threadIdx.x==0) eblk[blockIdx.x] = lds[0]+lds[1]+lds[2]+lds[3];
}

// ---------------- pass 2: thread owns M2 atoms, walks k-lines with phase recurrence.
// (SrG,SiG) reads are wave-uniform -> scalar cache. Field accumulated in lattice basis.
__global__ __launch_bounds__(NT2) void k_pass2(const float* __restrict__ coords,
        const float* __restrict__ box, const float* __restrict__ pk2p,
        float* __restrict__ part, int N, int NL, int kmax) {
    float b[9], bi[9];
    #pragma unroll
    for (int j=0;j<9;++j) b[j]=box[j];
    inv3(b, bi);
    int LINELEN = 2*kmax+1;
    int S2 = gridDim.y, s0 = blockIdx.y;
    int NSTEP = gridDim.x*NT2;
    int nbase = blockIdx.x*NT2 + threadIdx.x;
    float u1[M2],u2[M2],u3[M2],c3[M2],s3[M2];
    float pot[M2],F1[M2],F2[M2],F3[M2];
    #pragma unroll
    for (int m=0;m<M2;++m){
        int n = nbase + m*NSTEP;
        float rx=0.f,ry=0.f,rz=0.f;
        if (n < N){ rx=coords[3*n]; ry=coords[3*n+1]; rz=coords[3*n+2]; }
        u1[m] = bi[0]*rx + bi[1]*ry + bi[2]*rz;
        u2[m] = bi[3]*rx + bi[4]*ry + bi[5]*rz;
        u3[m] = bi[6]*rx + bi[7]*ry + bi[8]*rz;
        sincos2pi(u3[m], s3[m], c3[m]);
        pot[m]=0.f; F1[m]=0.f; F2[m]=0.f; F3[m]=0.f;
    }
    float fkzb = -(float)kmax;
    for (int lg = s0; lg*LL < NL; lg += S2) {
        int l0 = lg*LL, l1 = min(NL, l0+LL);
        for (int l = l0; l < l1; ++l) {
            int kxi, kyi;
            if (l == 0) { kxi=0; kyi=0; }
            else if (l <= kmax) { kxi=0; kyi=l; }
            else { int lp = l - kmax - 1; kxi = 1 + lp/LINELEN; kyi = lp - (kxi-1)*LINELEN - kmax; }
            float fkx = (float)kxi, fky = (float)kyi;
            const float* pl = pk2p + 2*(size_t)l*LINELEN;
            float cc[M2], ss[M2];
            #pragma unroll
            for (int m=0;m<M2;++m){
                float ub = fkx*u1[m] + fky*u2[m] + fkzb*u3[m];
                sincos2pi(ub, ss[m], cc[m]);
            }
            #pragma unroll 5
            for (int j=0;j<LINELEN;++j) {
                float srg = pl[2*j], sig = pl[2*j+1];
                float fkz = (float)(j - kmax);
                #pragma unroll
                for (int m=0;m<M2;++m){
                    pot[m] = fmaf(srg, cc[m], pot[m]);
                    pot[m] = fmaf(sig, ss[m], pot[m]);
                    float kim = srg*ss[m];
                    kim = fmaf(-sig, cc[m], kim);
                    F1[m] = fmaf(fkx, kim, F1[m]);
                    F2[m] = fmaf(fky, kim, F2[m]);
                    F3[m] = fmaf(fkz, kim, F3[m]);
                    float tmp = ss[m]*s3[m];
                    float cn = fmaf(cc[m], c3[m], -tmp);
                    float tmp2 = cc[m]*s3[m];
                    ss[m] = fmaf(ss[m], c3[m], tmp2);
                    cc[m] = cn;
                }
            }
        }
    }
    #pragma unroll
    for (int m=0;m<M2;++m) {
        int n = nbase + m*NSTEP;
        if (n < N) {
            float fx = F1[m]*bi[0] + F2[m]*bi[3] + F3[m]*bi[6];
            float fy = F1[m]*bi[1] + F2[m]*bi[4] + F3[m]*bi[7];
            float fz = F1[m]*bi[2] + F2[m]*bi[5] + F3[m]*bi[8];
            part[(size_t)(0*S2+s0)*N+n]=pot[m];
            part[(size_t)(1*S2+s0)*N+n]=fx;
            part[(size_t)(2*S2+s0)*N+n]=fy;
            part[(size_t)(3*S2+s0)*N+n]=fz;
        }
    }
}

// ---------------- finalize: block 0 = energy; blocks 1.. = one thread per output scalar
__global__ __launch_bounds__(NT) void k_fin(const float* __restrict__ part,
                      const float* __restrict__ q,
                      const float* __restrict__ p, const float* __restrict__ box,
                      const float* __restrict__ eblk, int nblk,
                      const float* __restrict__ selfp, int nself,
                      float* __restrict__ out, int N, int S2) {
    float b[9];
    #pragma unroll
    for (int j=0;j<9;++j) b[j]=box[j];
    float V = b[0]*(b[4]*b[8]-b[5]*b[7]) + b[1]*(b[5]*b[6]-b[3]*b[8]) + b[2]*(b[3]*b[7]-b[4]*b[6]);
    float arpi = ALPHA_F/sqrtf(PI_F);
    float a2 = ALPHA_F*ALPHA_F;
    if (blockIdx.x == 0) {
        int lane = threadIdx.x;
        if (lane >= 64) return;
        float e=0.f, sq=0.f, sp=0.f, st=0.f;
        for (int i=lane;i<nblk;i+=64) e += eblk[i];
        for (int i=lane;i<nself;i+=64){ sq+=selfp[4*i]; sp+=selfp[4*i+1]; st+=selfp[4*i+2]; }
        for (int o=32;o;o>>=1) {
            e += __shfl_down(e,o,64); sq += __shfl_down(sq,o,64);
            sp += __shfl_down(sp,o,64); st += __shfl_down(st,o,64);
        }
        if (lane==0) {
            out[0] = e/(PI_F*V) - arpi*sq - arpi*(2.0f*a2/3.0f)*sp
                   - arpi*(8.0f*a2*a2/45.0f)*st;
        }
        return;
    }
    int gid = (blockIdx.x-1)*NT + threadIdx.x;
    if (gid >= 4*N) return;
    int c = gid / N;
    int n = gid - c*N;
    float sum = 0.f;
    #pragma unroll 4
    for (int s=0;s<S2;++s) sum += part[(size_t)(c*S2+s)*N+n];
    if (c == 0) {
        out[1+n] = (2.0f/(PI_F*V))*sum - 2.0f*arpi*q[n];
    } else {
        float cp2 = arpi*(4.0f*a2/3.0f);
        out[1+N+3*n+(c-1)] = (4.0f/V)*sum + cp2*p[3*n+(c-1)];
    }
}

extern "C" void kernel_launch(void* const* d_in, const int* in_sizes, int n_in,
                              void* d_out, int out_size, void* d_ws, size_t ws_size,
                              hipStream_t stream) {
    const float* coords = (const float*)d_in[0];
    const float* box    = (const float*)d_in[1];
    const float* q      = (const float*)d_in[2];
    const float* p      = (const float*)d_in[3];
    const float* t      = (const float*)d_in[4];
    const float* kvecs  = (const float*)d_in[5];
    int N = in_sizes[0]/3;
    int K = in_sizes[5]/3;
    float* ws = (float*)d_ws;
    size_t ws_floats = ws_size / 4;

    // derive kmax from K = kmax*((2kmax+1)^2 + (2kmax+1) + 1)
    int kmax = 12;
    for (int km=1; km<=40; ++km) {
        long ll = 2l*km+1;
        if ((long)km*(ll*ll + ll + 1) == (long)K) { kmax = km; break; }
    }
    int LINELEN = 2*kmax+1;                 // 25
    int NL = 1 + kmax + kmax*LINELEN;       // 313
    int SEGPL = (LINELEN + L1 - 1)/L1;      // 5
    int LPAD = SEGPL*L1;                    // 25
    int K2 = NL*LPAD;                       // 7825
    int NSEG = NL*SEGPL;                    // 1565

    int kb = (K + NT - 1)/NT;               // 31
    int nb = (N + NT - 1)/NT;               // 24

    int S1 = (N + ACHUNK - 1)/ACHUNK;       // 150
    int S2 = (NL + LL - 1)/LL;              // 157

    auto need = [&](int s1, int s2)->size_t {
        return (size_t)K + 2*(size_t)NL*LINELEN + 16*(size_t)N + 16
             + 2*(size_t)s1*K2 + 2*(size_t)RS*K
             + 4*(size_t)nb + 256 + (size_t)kb + 64
             + 4*(size_t)s2*N;
    };
    while (need(S1,S2) > ws_floats && (S1 > 2 || S2 > 2)) {
        size_t b1 = 2*(size_t)S1*K2, b2 = 4*(size_t)S2*N;
        if (b2 >= b1 && S2 > 2) S2 = (S2+1)/2;
        else S1 = (S1+1)/2;
    }

    size_t off = 0;
    float* gk     = ws + off; off += (size_t)K;
    float* pk2p   = ws + off; off += 2*(size_t)NL*LINELEN;
    float* atom16 = ws + off; off += 16*(size_t)N + 16;
    float* psr    = ws + off; off += (size_t)S1*K2;
    float* psi    = ws + off; off += (size_t)S1*K2;
    float* pred   = ws + off; off += 2*(size_t)RS*K;
    float* selfp  = ws + off; off += 4*(size_t)nb + 256;
    float* eblk   = ws + off; off += (size_t)kb + 64;
    float* part   = ws + off; off += 4*(size_t)S2*N;

    k_prep<<<kb + nb, NT, 0, stream>>>(box, kvecs, coords, q, p, t,
                                       gk, pk2p, atom16, selfp, K, N, kb, kmax);

    int gx1 = (NSEG + NT1 - 1)/NT1;          // 13
    dim3 g1(gx1, S1);
    k_pass1<<<g1, NT1, 0, stream>>>(atom16, psr, psi, N, kmax, NL, SEGPL, LPAD, K2);

    dim3 gr1(kb, RS);
    k_reduce1<<<gr1, NT, 0, stream>>>(psr, psi, pred, K, K2, S1, kmax, LPAD);
    k_reduce2<<<kb, NT, 0, stream>>>(pred, gk, pk2p, eblk, K, kmax);

    int nthr2 = (N + M2 - 1)/M2;
    int gx2 = (nthr2 + NT2 - 1)/NT2;         // 12
    dim3 g2(gx2, S2);
    k_pass2<<<g2, NT2, 0, stream>>>(coords, box, pk2p, part, N, NL, kmax);

    int outb = (4*N + NT - 1)/NT + 1;
    k_fin<<<outb, NT, 0, stream>>>(part, q, p, box, eblk, kb, selfp, nb,
                                   (float*)d_out, N, S2);
}